// Round 5
// baseline (841.432 us; speedup 1.0000x reference)
//
#include <hip/hip_runtime.h>
#include <hip/hip_bf16.h>
#include <math.h>

#define S_LEN 2048
#define D_DIM 2048
#define NHEAD 16
#define HD_DIM 128
#define NROWS 4096   // B*S
#define BSD 8388608  // NROWS*D_DIM elements (16.78 MB as bf16)

typedef __bf16 bf16x8 __attribute__((ext_vector_type(8)));
typedef float f32x4 __attribute__((ext_vector_type(4)));
typedef unsigned short u16;
typedef unsigned int u32;

__device__ __forceinline__ float bf2f(u16 h) {
    union { u32 u; float f; } v; v.u = ((u32)h) << 16; return v.f;
}
__device__ __forceinline__ u16 f2bf(float f) {
    union { float f; u32 u; } v; v.f = f;
    u32 r = v.u + 0x7fffu + ((v.u >> 16) & 1u);
    return (u16)(r >> 16);
}

// async global->LDS, 16B per lane
__device__ __forceinline__ void gld16(const void* g, void* l) {
    __builtin_amdgcn_global_load_lds((const __attribute__((address_space(1))) void*)g,
                                     (__attribute__((address_space(3))) void*)l,
                                     16, 0, 0);
}

// Dtype sniff (validated R5/R6: fires f32 on this harness).
__device__ __forceinline__ bool detect_f32(const void* p) {
    const u16* h = (const u16*)p;
    int sane = 0;
    for (int i = 0; i < 128; i++) {
        const u16 v = h[2 * i];
        const int e = (v >> 7) & 0xFF;
        sane += (int)((e >= 96 && e <= 150) || ((v & 0x7FFF) == 0));
    }
    return sane < 64;
}

__device__ __forceinline__ bf16x8 load8(const void* X, size_t eidx, bool f32) {
    if (!f32) return *(const bf16x8*)((const u16*)X + eidx);
    const float* xf = (const float*)X + eidx;
    const f32x4 a = *(const f32x4*)xf;
    const f32x4 b = *(const f32x4*)(xf + 4);
    bf16x8 r;
    u16* rp = (u16*)&r;
    rp[0] = f2bf(a[0]); rp[1] = f2bf(a[1]); rp[2] = f2bf(a[2]); rp[3] = f2bf(a[3]);
    rp[4] = f2bf(b[0]); rp[5] = f2bf(b[1]); rp[6] = f2bf(b[2]); rp[7] = f2bf(b[3]);
    return r;
}

__device__ __forceinline__ float bload(const void* b, int i, bool f32) {
    return f32 ? ((const float*)b)[i] : bf2f(((const u16*)b)[i]);
}

// ---------- diagnostic fill ----------
__global__ __launch_bounds__(256) void fill_k(float* __restrict__ out, float v, int n) {
    const int i = blockIdx.x * 256 + threadIdx.x;
    if (i < n) out[i] = v;
}

// ---------- activation f32 -> bf16 (or bf16 copy), 8 elems/thread ----------
__device__ __forceinline__ void conv_body(const void* __restrict__ in,
                                          u16* __restrict__ out, bool f32) {
    const size_t i = ((size_t)blockIdx.x * 256 + threadIdx.x) << 3;
    if (f32) {
        const f32x4 a = *(const f32x4*)((const float*)in + i);
        const f32x4 b = *(const f32x4*)((const float*)in + i + 4);
        uint4 w;
        w.x = (u32)f2bf(a[0]) | ((u32)f2bf(a[1]) << 16);
        w.y = (u32)f2bf(a[2]) | ((u32)f2bf(a[3]) << 16);
        w.z = (u32)f2bf(b[0]) | ((u32)f2bf(b[1]) << 16);
        w.w = (u32)f2bf(b[2]) | ((u32)f2bf(b[3]) << 16);
        *(uint4*)&out[i] = w;
    } else {
        *(uint4*)&out[i] = *(const uint4*)&((const u16*)in)[i];
    }
}

__global__ __launch_bounds__(256) void conv_bf16(const void* __restrict__ in,
                                                 u16* __restrict__ out) {
    conv_body(in, out, detect_f32(in));
}

// fused 3-stream conversion: y selects q/k/v
__global__ __launch_bounds__(256) void conv3(const void* __restrict__ q,
                                             const void* __restrict__ k,
                                             const void* __restrict__ v,
                                             u16* __restrict__ oq,
                                             u16* __restrict__ ok,
                                             u16* __restrict__ ov) {
    const int z = blockIdx.y;
    const void* in = (z == 0) ? q : (z == 1) ? k : v;
    u16* out = (z == 0) ? oq : (z == 1) ? ok : ov;
    conv_body(in, out, detect_f32(in));
}

// ---------- W transpose helper (device): [K,N] tile -> bf16 [N,K] ----------
__device__ __forceinline__ void transpose_body(const void* __restrict__ W,
                                               u16* __restrict__ out) {
    __shared__ float tile[64][68];
    const bool f32w = detect_f32(W);
    const int t = threadIdx.x;
    const int r = t >> 4, c4 = (t & 15) << 2;
    const int kb = blockIdx.y << 6, nb = blockIdx.x << 6;
    if (f32w) {
        #pragma unroll
        for (int i = 0; i < 4; i++) {
            const f32x4 v = *(const f32x4*)((const float*)W +
                (size_t)(kb + r + 16 * i) * D_DIM + nb + c4);
            tile[r + 16 * i][c4 + 0] = v[0];
            tile[r + 16 * i][c4 + 1] = v[1];
            tile[r + 16 * i][c4 + 2] = v[2];
            tile[r + 16 * i][c4 + 3] = v[3];
        }
    } else {
        #pragma unroll
        for (int i = 0; i < 4; i++)
            #pragma unroll
            for (int j = 0; j < 4; j++)
                tile[r + 16 * i][c4 + j] =
                    bf2f(((const u16*)W)[(size_t)(kb + r + 16 * i) * D_DIM + nb + c4 + j]);
    }
    __syncthreads();
    #pragma unroll
    for (int i = 0; i < 4; i++) {
        const int n = nb + r + 16 * i;
        u16 pk[4];
        #pragma unroll
        for (int j = 0; j < 4; j++) pk[j] = f2bf(tile[c4 + j][r + 16 * i]);
        *(uint2*)&out[(size_t)n * D_DIM + kb + c4] = *(uint2*)pk;
    }
}

__global__ __launch_bounds__(256) void transpose_w(const void* __restrict__ W,
                                                   u16* __restrict__ out) {
    transpose_body(W, out);
}

// fused: z selects Wq/Wk/Wv -> slot z
__global__ __launch_bounds__(256) void transpose_all(const void* __restrict__ W0,
                                                     const void* __restrict__ W1,
                                                     const void* __restrict__ W2,
                                                     u16* __restrict__ out) {
    const int z = blockIdx.z;
    const void* W = (z == 0) ? W0 : (z == 1) ? W1 : W2;
    transpose_body(W, out + (size_t)z * D_DIM * D_DIM);
}

// ---------- fused QKV GEMM, all-bf16, single-barrier dbuf (T3-minimum) ----------
// A: bf16 row-major via gld16; B: bf16 WT slot z via gld16; stage k+1 while
// computing k; ONE __syncthreads per K-step (drains vmcnt -> staged tile ready).
__global__ __launch_bounds__(256) void qkv_gemm_bf(const u16* __restrict__ Xq,
                                                   const u16* __restrict__ Xk,
                                                   const u16* __restrict__ Xv,
                                                   const u16* __restrict__ WTbase,
                                                   const void* __restrict__ bqp,
                                                   const void* __restrict__ bkp,
                                                   const void* __restrict__ bvp,
                                                   u16* __restrict__ Oq,
                                                   u16* __restrict__ Ok,
                                                   u16* __restrict__ Ov) {
    __shared__ __align__(16) u16 a_s[2][128 * 32];
    __shared__ __align__(16) u16 b_s[2][128 * 32];
    const int z = blockIdx.z;
    const u16* X    = (z == 0) ? Xq  : (z == 1) ? Xk  : Xv;
    const void* bias= (z == 0) ? bqp : (z == 1) ? bkp : bvp;
    u16* out        = (z == 0) ? Oq  : (z == 1) ? Ok  : Ov;
    const u16* WT   = WTbase + (size_t)z * D_DIM * D_DIM;
    const bool f32b = detect_f32(bias);
    const int t = threadIdx.x;
    const int wave = t >> 6, lane = t & 63;
    const int quad = lane >> 4, m16 = lane & 15;
    const int wm = (wave >> 1) << 6, wn = (wave & 1) << 6;
    const int rowBase = blockIdx.y << 7, colBase = blockIdx.x << 7;
    const int arow = t >> 2, aoff = (t & 3) << 3;

    f32x4 acc[4][4];
    #pragma unroll
    for (int i = 0; i < 4; i++)
        #pragma unroll
        for (int j = 0; j < 4; j++) acc[i][j] = (f32x4){0.f, 0.f, 0.f, 0.f};

    // prologue stage of tile 0
    gld16(&X[(size_t)(rowBase + arow) * D_DIM + aoff],        &a_s[0][t * 8]);
    gld16(&X[(size_t)(rowBase + arow + 64) * D_DIM + aoff],   &a_s[0][(t + 256) * 8]);
    gld16(&WT[(size_t)(colBase + arow) * D_DIM + aoff],       &b_s[0][t * 8]);
    gld16(&WT[(size_t)(colBase + arow + 64) * D_DIM + aoff],  &b_s[0][(t + 256) * 8]);
    __syncthreads();

    int cur = 0;
    for (int k0 = 0; k0 < D_DIM; k0 += 32, cur ^= 1) {
        if (k0 + 32 < D_DIM) {
            const int kn = k0 + 32;
            gld16(&X[(size_t)(rowBase + arow) * D_DIM + kn + aoff],       &a_s[cur ^ 1][t * 8]);
            gld16(&X[(size_t)(rowBase + arow + 64) * D_DIM + kn + aoff],  &a_s[cur ^ 1][(t + 256) * 8]);
            gld16(&WT[(size_t)(colBase + arow) * D_DIM + kn + aoff],      &b_s[cur ^ 1][t * 8]);
            gld16(&WT[(size_t)(colBase + arow + 64) * D_DIM + kn + aoff], &b_s[cur ^ 1][(t + 256) * 8]);
        }
        bf16x8 af[4], bfr[4];
        #pragma unroll
        for (int mi = 0; mi < 4; mi++)
            af[mi] = *(bf16x8*)&a_s[cur][(wm + mi * 16 + m16) * 32 + quad * 8];
        #pragma unroll
        for (int ni = 0; ni < 4; ni++)
            bfr[ni] = *(bf16x8*)&b_s[cur][(wn + ni * 16 + m16) * 32 + quad * 8];
        #pragma unroll
        for (int mi = 0; mi < 4; mi++)
            #pragma unroll
            for (int ni = 0; ni < 4; ni++)
                acc[mi][ni] = __builtin_amdgcn_mfma_f32_16x16x32_bf16(
                    af[mi], bfr[ni], acc[mi][ni], 0, 0, 0);
        __syncthreads();   // staged tile landed; reads of [cur] done
    }

    #pragma unroll
    for (int ni = 0; ni < 4; ni++) {
        const int col = colBase + wn + ni * 16 + m16;
        const float bv = bload(bias, col, f32b);
        const int h = col >> 7, hd = col & (HD_DIM - 1);
        #pragma unroll
        for (int mi = 0; mi < 4; mi++) {
            #pragma unroll
            for (int r = 0; r < 4; r++) {
                const int row = rowBase + wm + mi * 16 + quad * 4 + r;
                const int b = row >> 11, s = row & (S_LEN - 1);
                out[(((size_t)(b * NHEAD + h)) * S_LEN + s) * HD_DIM + hd] =
                    f2bf(acc[mi][ni][r] + bv);
            }
        }
    }
}

// ---------- fused QKV GEMM, f32 A (R3-validated; mid-tier ws fallback) ----------
__global__ __launch_bounds__(256) void qkv_gemm(const void* __restrict__ Xq,
                                                const void* __restrict__ Xk,
                                                const void* __restrict__ Xv,
                                                const u16* __restrict__ WTbase,
                                                const void* __restrict__ bqp,
                                                const void* __restrict__ bkp,
                                                const void* __restrict__ bvp,
                                                u16* __restrict__ Oq,
                                                u16* __restrict__ Ok,
                                                u16* __restrict__ Ov) {
    __shared__ __align__(16) u16 a_s[128 * 32];
    __shared__ __align__(16) u16 b_s[128 * 32];
    const int z = blockIdx.z;
    const void* X   = (z == 0) ? Xq  : (z == 1) ? Xk  : Xv;
    const void* bias= (z == 0) ? bqp : (z == 1) ? bkp : bvp;
    u16* out        = (z == 0) ? Oq  : (z == 1) ? Ok  : Ov;
    const u16* WT   = WTbase + (size_t)z * D_DIM * D_DIM;
    const bool f32x = detect_f32(X);
    const bool f32b = detect_f32(bias);
    const int t = threadIdx.x;
    const int wave = t >> 6, lane = t & 63;
    const int quad = lane >> 4, m16 = lane & 15;
    const int wm = (wave >> 1) << 6, wn = (wave & 1) << 6;
    const int rowBase = blockIdx.y << 7, colBase = blockIdx.x << 7;
    const int arow = t >> 2, aoff = (t & 3) << 3;

    f32x4 acc[4][4];
    #pragma unroll
    for (int i = 0; i < 4; i++)
        #pragma unroll
        for (int j = 0; j < 4; j++) acc[i][j] = (f32x4){0.f, 0.f, 0.f, 0.f};

    for (int k0 = 0; k0 < D_DIM; k0 += 32) {
        const bf16x8 av0 = load8(X, (size_t)(rowBase + arow) * D_DIM + k0 + aoff, f32x);
        const bf16x8 av1 = load8(X, (size_t)(rowBase + arow + 64) * D_DIM + k0 + aoff, f32x);
        __syncthreads();
        *(bf16x8*)&a_s[arow * 32 + aoff]        = av0;
        *(bf16x8*)&a_s[(arow + 64) * 32 + aoff] = av1;
        gld16(&WT[(size_t)(colBase + arow) * D_DIM + k0 + aoff],      &b_s[t * 8]);
        gld16(&WT[(size_t)(colBase + arow + 64) * D_DIM + k0 + aoff], &b_s[(t + 256) * 8]);
        __syncthreads();

        bf16x8 af[4], bfr[4];
        #pragma unroll
        for (int mi = 0; mi < 4; mi++)
            af[mi] = *(bf16x8*)&a_s[(wm + mi * 16 + m16) * 32 + quad * 8];
        #pragma unroll
        for (int ni = 0; ni < 4; ni++)
            bfr[ni] = *(bf16x8*)&b_s[(wn + ni * 16 + m16) * 32 + quad * 8];
        #pragma unroll
        for (int mi = 0; mi < 4; mi++)
            #pragma unroll
            for (int ni = 0; ni < 4; ni++)
                acc[mi][ni] = __builtin_amdgcn_mfma_f32_16x16x32_bf16(
                    af[mi], bfr[ni], acc[mi][ni], 0, 0, 0);
    }

    #pragma unroll
    for (int ni = 0; ni < 4; ni++) {
        const int col = colBase + wn + ni * 16 + m16;
        const float bv = bload(bias, col, f32b);
        const int h = col >> 7, hd = col & (HD_DIM - 1);
        #pragma unroll
        for (int mi = 0; mi < 4; mi++) {
            #pragma unroll
            for (int r = 0; r < 4; r++) {
                const int row = rowBase + wm + mi * 16 + quad * 4 + r;
                const int b = row >> 11, s = row & (S_LEN - 1);
                out[(((size_t)(b * NHEAD + h)) * S_LEN + s) * HD_DIM + hd] =
                    f2bf(acc[mi][ni][r] + bv);
            }
        }
    }
}

// ---------- 128x128-tile GEMM vs pre-transposed bf16 WT [N,K] ----------
// MODE 0: f32 A reg-staged (legacy 2-barrier). MODE 2: bf16 row-major A.
// MODE 1: bf16 head-major A -> fp32 out. Modes 1/2: single-barrier dbuf.
template<int MODE>
__global__ __launch_bounds__(256) void bt_gemm(const void* __restrict__ X,
                                               const u16* __restrict__ WT,
                                               const void* __restrict__ bias,
                                               void* __restrict__ out) {
    const bool f32b = detect_f32(bias);
    const int t = threadIdx.x;
    const int wave = t >> 6, lane = t & 63;
    const int quad = lane >> 4, m16 = lane & 15;
    const int wm = (wave >> 1) << 6, wn = (wave & 1) << 6;
    const int rowBase = blockIdx.y << 7, colBase = blockIdx.x << 7;
    const int arow = t >> 2, aoff = (t & 3) << 3;

    f32x4 acc[4][4];
    #pragma unroll
    for (int i = 0; i < 4; i++)
        #pragma unroll
        for (int j = 0; j < 4; j++) acc[i][j] = (f32x4){0.f, 0.f, 0.f, 0.f};

    if constexpr (MODE == 0) {
        __shared__ __align__(16) u16 a_s[128 * 32];
        __shared__ __align__(16) u16 b_s[128 * 32];
        const bool f32x = detect_f32(X);
        for (int k0 = 0; k0 < D_DIM; k0 += 32) {
            const bf16x8 av0 = load8(X, (size_t)(rowBase + arow) * D_DIM + k0 + aoff, f32x);
            const bf16x8 av1 = load8(X, (size_t)(rowBase + arow + 64) * D_DIM + k0 + aoff, f32x);
            __syncthreads();
            *(bf16x8*)&a_s[arow * 32 + aoff]        = av0;
            *(bf16x8*)&a_s[(arow + 64) * 32 + aoff] = av1;
            gld16(&WT[(size_t)(colBase + arow) * D_DIM + k0 + aoff],      &b_s[t * 8]);
            gld16(&WT[(size_t)(colBase + arow + 64) * D_DIM + k0 + aoff], &b_s[(t + 256) * 8]);
            __syncthreads();

            bf16x8 af[4], bfr[4];
            #pragma unroll
            for (int mi = 0; mi < 4; mi++)
                af[mi] = *(bf16x8*)&a_s[(wm + mi * 16 + m16) * 32 + quad * 8];
            #pragma unroll
            for (int ni = 0; ni < 4; ni++)
                bfr[ni] = *(bf16x8*)&b_s[(wn + ni * 16 + m16) * 32 + quad * 8];
            #pragma unroll
            for (int mi = 0; mi < 4; mi++)
                #pragma unroll
                for (int ni = 0; ni < 4; ni++)
                    acc[mi][ni] = __builtin_amdgcn_mfma_f32_16x16x32_bf16(
                        af[mi], bfr[ni], acc[mi][ni], 0, 0, 0);
        }
    } else {
        __shared__ __align__(16) u16 a_s[2][128 * 32];
        __shared__ __align__(16) u16 b_s[2][128 * 32];
        // stage tile (k0) into buffer buf
        #define STAGE_T(buf, kk)                                                          \
            do {                                                                          \
                if (MODE == 2) {                                                          \
                    gld16(&((const u16*)X)[(size_t)(rowBase + arow) * D_DIM + (kk) + aoff],      \
                          &a_s[buf][t * 8]);                                              \
                    gld16(&((const u16*)X)[(size_t)(rowBase + arow + 64) * D_DIM + (kk) + aoff], \
                          &a_s[buf][(t + 256) * 8]);                                      \
                } else {                                                                  \
                    const int kg = (kk) + aoff, hh = kg >> 7, hd2 = kg & (HD_DIM - 1);    \
                    const int r0 = rowBase + arow, r1 = r0 + 64;                          \
                    gld16(&((const u16*)X)[                                               \
                        (((size_t)((r0 >> 11) * NHEAD + hh)) * S_LEN + (r0 & (S_LEN - 1))) * HD_DIM + hd2], \
                        &a_s[buf][t * 8]);                                                \
                    gld16(&((const u16*)X)[                                               \
                        (((size_t)((r1 >> 11) * NHEAD + hh)) * S_LEN + (r1 & (S_LEN - 1))) * HD_DIM + hd2], \
                        &a_s[buf][(t + 256) * 8]);                                        \
                }                                                                         \
                gld16(&WT[(size_t)(colBase + arow) * D_DIM + (kk) + aoff],      &b_s[buf][t * 8]);        \
                gld16(&WT[(size_t)(colBase + arow + 64) * D_DIM + (kk) + aoff], &b_s[buf][(t + 256) * 8]);\
            } while (0)

        STAGE_T(0, 0);
        __syncthreads();
        int cur = 0;
        for (int k0 = 0; k0 < D_DIM; k0 += 32, cur ^= 1) {
            if (k0 + 32 < D_DIM) STAGE_T(cur ^ 1, k0 + 32);
            bf16x8 af[4], bfr[4];
            #pragma unroll
            for (int mi = 0; mi < 4; mi++)
                af[mi] = *(bf16x8*)&a_s[cur][(wm + mi * 16 + m16) * 32 + quad * 8];
            #pragma unroll
            for (int ni = 0; ni < 4; ni++)
                bfr[ni] = *(bf16x8*)&b_s[cur][(wn + ni * 16 + m16) * 32 + quad * 8];
            #pragma unroll
            for (int mi = 0; mi < 4; mi++)
                #pragma unroll
                for (int ni = 0; ni < 4; ni++)
                    acc[mi][ni] = __builtin_amdgcn_mfma_f32_16x16x32_bf16(
                        af[mi], bfr[ni], acc[mi][ni], 0, 0, 0);
            __syncthreads();
        }
        #undef STAGE_T
    }

    #pragma unroll
    for (int ni = 0; ni < 4; ni++) {
        const int col = colBase + wn + ni * 16 + m16;
        const float bv = bload(bias, col, f32b);
        const int h = col >> 7, hd = col & (HD_DIM - 1);
        #pragma unroll
        for (int mi = 0; mi < 4; mi++) {
            #pragma unroll
            for (int r = 0; r < 4; r++) {
                const int row = rowBase + wm + mi * 16 + quad * 4 + r;
                const float v = acc[mi][ni][r] + bv;
                if (MODE == 1) {
                    ((float*)out)[(size_t)row * D_DIM + col] = v;
                } else {
                    const int b = row >> 11, s = row & (S_LEN - 1);
                    ((u16*)out)[(((size_t)(b * NHEAD + h)) * S_LEN + s) * HD_DIM + hd] = f2bf(v);
                }
            }
        }
    }
}

// ---------- FALLBACK 64-tile GEMMs (validated R6/R7; used if ws too small) ----------
__global__ __launch_bounds__(256) void gemm_qkv(const void* __restrict__ X,
                                                const void* __restrict__ W,
                                                const void* __restrict__ bias,
                                                u16* __restrict__ out) {
    __shared__ __align__(16) u16 a_s[64 * 32];
    __shared__ __align__(16) u16 b_s[64 * 40];
    const bool f32x = detect_f32(X);
    const bool f32w = detect_f32(W);
    const bool f32b = detect_f32(bias);
    const int t = threadIdx.x;
    const int wave = t >> 6, lane = t & 63;
    const int quad = lane >> 4, mrow = lane & 15;
    const int rowBase = blockIdx.y * 64;
    const int colBase = blockIdx.x * 64;
    const int srow = t >> 2, soff = (t & 3) << 3;
    const int krow = t >> 3, ncol0 = (t & 7) << 3;

    f32x4 acc0 = {0.f, 0.f, 0.f, 0.f};
    f32x4 acc1 = acc0, acc2 = acc0, acc3 = acc0;

    for (int k0 = 0; k0 < D_DIM; k0 += 32) {
        const bf16x8 av = load8(X, (size_t)(rowBase + srow) * D_DIM + k0 + soff, f32x);
        const bf16x8 wv = load8(W, (size_t)(k0 + krow) * D_DIM + colBase + ncol0, f32w);
        __syncthreads();
        *(bf16x8*)&a_s[srow * 32 + soff] = av;
        const u16* wp = (const u16*)&wv;
        #pragma unroll
        for (int j = 0; j < 8; j++) b_s[(ncol0 + j) * 40 + krow] = wp[j];
        __syncthreads();
        const bf16x8 af  = *(bf16x8*)&a_s[(wave * 16 + mrow) * 32 + (quad << 3)];
        const bf16x8 bf0 = *(bf16x8*)&b_s[(     mrow) * 40 + (quad << 3)];
        const bf16x8 bf1 = *(bf16x8*)&b_s[(16 + mrow) * 40 + (quad << 3)];
        const bf16x8 bf2 = *(bf16x8*)&b_s[(32 + mrow) * 40 + (quad << 3)];
        const bf16x8 bf3 = *(bf16x8*)&b_s[(48 + mrow) * 40 + (quad << 3)];
        acc0 = __builtin_amdgcn_mfma_f32_16x16x32_bf16(af, bf0, acc0, 0, 0, 0);
        acc1 = __builtin_amdgcn_mfma_f32_16x16x32_bf16(af, bf1, acc1, 0, 0, 0);
        acc2 = __builtin_amdgcn_mfma_f32_16x16x32_bf16(af, bf2, acc2, 0, 0, 0);
        acc3 = __builtin_amdgcn_mfma_f32_16x16x32_bf16(af, bf3, acc3, 0, 0, 0);
    }

    const f32x4 accs[4] = {acc0, acc1, acc2, acc3};
    #pragma unroll
    for (int cb = 0; cb < 4; cb++) {
        const int col = colBase + cb * 16 + mrow;
        const float bv = bload(bias, col, f32b);
        const int h = col >> 7, hd = col & (HD_DIM - 1);
        #pragma unroll
        for (int r = 0; r < 4; r++) {
            const int row = rowBase + wave * 16 + quad * 4 + r;
            const int b = row >> 11, s = row & (S_LEN - 1);
            out[(((size_t)(b * NHEAD + h)) * S_LEN + s) * HD_DIM + hd] =
                f2bf(accs[cb][r] + bv);
        }
    }
}

__global__ __launch_bounds__(256) void gemm_o(const u16* __restrict__ A,
                                              const void* __restrict__ W,
                                              const void* __restrict__ bias,
                                              float* __restrict__ out) {
    __shared__ __align__(16) u16 a_s[64 * 32];
    __shared__ __align__(16) u16 b_s[64 * 40];
    const bool f32w = detect_f32(W);
    const bool f32b = detect_f32(bias);
    const int t = threadIdx.x;
    const int wave = t >> 6, lane = t & 63;
    const int quad = lane >> 4, mrow = lane & 15;
    const int rowBase = blockIdx.y * 64;
    const int colBase = blockIdx.x * 64;
    const int srow = t >> 2, soff = (t & 3) << 3;
    const int krow = t >> 3, ncol0 = (t & 7) << 3;

    f32x4 acc0 = {0.f, 0.f, 0.f, 0.f};
    f32x4 acc1 = acc0, acc2 = acc0, acc3 = acc0;

    const int row = rowBase + srow;
    const int rb = row >> 11, rs = row & (S_LEN - 1);

    for (int k0 = 0; k0 < D_DIM; k0 += 32) {
        const int kg = k0 + soff;
        const int h = kg >> 7, hd = kg & (HD_DIM - 1);
        const bf16x8 av = *(const bf16x8*)&A[
            (((size_t)(rb * NHEAD + h)) * S_LEN + rs) * HD_DIM + hd];
        const bf16x8 wv = load8(W, (size_t)(k0 + krow) * D_DIM + colBase + ncol0, f32w);
        __syncthreads();
        *(bf16x8*)&a_s[srow * 32 + soff] = av;
        const u16* wp = (const u16*)&wv;
        #pragma unroll
        for (int j = 0; j < 8; j++) b_s[(ncol0 + j) * 40 + krow] = wp[j];
        __syncthreads();
        const bf16x8 af  = *(bf16x8*)&a_s[(wave * 16 + mrow) * 32 + (quad << 3)];
        const bf16x8 bf0 = *(bf16x8*)&b_s[(     mrow) * 40 + (quad << 3)];
        const bf16x8 bf1 = *(bf16x8*)&b_s[(16 + mrow) * 40 + (quad << 3)];
        const bf16x8 bf2 = *(bf16x8*)&b_s[(32 + mrow) * 40 + (quad << 3)];
        const bf16x8 bf3 = *(bf16x8*)&b_s[(48 + mrow) * 40 + (quad << 3)];
        acc0 = __builtin_amdgcn_mfma_f32_16x16x32_bf16(af, bf0, acc0, 0, 0, 0);
        acc1 = __builtin_amdgcn_mfma_f32_16x16x32_bf16(af, bf1, acc1, 0, 0, 0);
        acc2 = __builtin_amdgcn_mfma_f32_16x16x32_bf16(af, bf2, acc2, 0, 0, 0);
        acc3 = __builtin_amdgcn_mfma_f32_16x16x32_bf16(af, bf3, acc3, 0, 0, 0);
    }

    const f32x4 accs[4] = {acc0, acc1, acc2, acc3};
    #pragma unroll
    for (int cb = 0; cb < 4; cb++) {
        const int col = colBase + cb * 16 + mrow;
        const float bv = bload(bias, col, f32b);
        #pragma unroll
        for (int r = 0; r < 4; r++) {
            const int orow = rowBase + wave * 16 + quad * 4 + r;
            out[(size_t)orow * D_DIM + col] = accs[cb][r] + bv;
        }
    }
}

// ---------- RoPE in-place, [B,16,S,HD]; cos/sin fp32 ----------
__global__ __launch_bounds__(256) void rope_k(u16* __restrict__ q, u16* __restrict__ k) {
    const int idx = blockIdx.x * 256 + threadIdx.x;
    u16* p = blockIdx.y ? k : q;
    const int i  = idx & 63;
    const int s  = (idx >> 6) & (S_LEN - 1);
    const int bh = idx >> 17;
    const size_t base = ((size_t)bh * S_LEN + s) * HD_DIM;
    const float inv = __expf((float)i * -0.14391157f);
    const float ang = (float)s * inv;
    const float c = cosf(ang), sn = sinf(ang);
    const float x1 = bf2f(p[base + i]);
    const float x2 = bf2f(p[base + 64 + i]);
    p[base + i]      = f2bf(x1 * c - x2 * sn);
    p[base + 64 + i] = f2bf(x2 * c + x1 * sn);
}

// V^T LDS swizzle (validated R1): row d holds kv in 8-elem blocks permuted.
__device__ __forceinline__ int vswz(int d, int blk8) {
    return d * 72 + (((blk8) ^ ((d ^ (d >> 3)) & 7)) << 3);
}

// ---------- flash v3 (validated R1/R2: 232 us) — fallback paths ----------
__global__ __launch_bounds__(256, 3) void flash_mfma(const u16* Q,
                                                     const u16* __restrict__ K,
                                                     const u16* __restrict__ V,
                                                     u16* Out) {
    __shared__ __align__(16) u16 k_s[64 * 136];
    __shared__ __align__(16) u16 v_s[128 * 72];
    __shared__ __align__(16) u16 p_s[64 * 72];
    const int t = threadIdx.x;
    const int wave = t >> 6, lane = t & 63;
    const int quad = lane >> 4, m16 = lane & 15;
    const int h = blockIdx.y, b = blockIdx.z;
    const int q0 = (int)(gridDim.x - 1 - blockIdx.x) << 6;
    const size_t bhoff = ((size_t)(b * NHEAD + h)) * S_LEN * HD_DIM;

    #pragma unroll
    for (int i = 0; i < 4; i++) {
        const int chunk = t + 256 * i;
        const int row = chunk >> 4, d0 = (chunk & 15) << 3;
        *(uint4*)&k_s[row * 136 + d0] =
            *(const uint4*)&Q[bhoff + (size_t)(q0 + row) * HD_DIM + d0];
    }
    __syncthreads();
    bf16x8 qf[4];
    #pragma unroll
    for (int kc = 0; kc < 4; kc++)
        qf[kc] = *(bf16x8*)&k_s[(wave * 16 + m16) * 136 + kc * 32 + quad * 8];

    f32x4 o[8];
    #pragma unroll
    for (int i = 0; i < 8; i++) o[i] = (f32x4){0.f, 0.f, 0.f, 0.f};
    f32x4 m_i = {-1e30f, -1e30f, -1e30f, -1e30f};
    f32x4 l_i = {0.f, 0.f, 0.f, 0.f};

    const int row_g0 = q0 + wave * 16 + quad * 4;
    const float scale = 0.08838834764831843f;
    const int nt = (q0 >> 6) + 1;

    const int krow = t >> 4, kd0 = (t & 15) << 3;
    const int dg = t & 15, kvg = t >> 4;
    const int vsub = (kvg & 1) << 2;

    uint4 kreg[4], vreg[4];
    #pragma unroll
    for (int i = 0; i < 4; i++) {
        kreg[i] = *(const uint4*)&K[bhoff + (size_t)(krow + 16 * i) * HD_DIM + kd0];
        vreg[i] = *(const uint4*)&V[bhoff + (size_t)(kvg * 4 + i) * HD_DIM + dg * 8];
    }

    for (int it = 0; it < nt; ++it) {
        const int kb = it << 6;
        __syncthreads();
        #pragma unroll
        for (int i = 0; i < 4; i++)
            *(uint4*)&k_s[(krow + 16 * i) * 136 + kd0] = kreg[i];
        {
            const u16* v0 = (const u16*)&vreg[0];
            const u16* v1 = (const u16*)&vreg[1];
            const u16* v2 = (const u16*)&vreg[2];
            const u16* v3 = (const u16*)&vreg[3];
            #pragma unroll
            for (int j = 0; j < 8; j++) {
                const int d = dg * 8 + j;
                uint2 w;
                w.x = (u32)v0[j] | ((u32)v1[j] << 16);
                w.y = (u32)v2[j] | ((u32)v3[j] << 16);
                *(uint2*)&v_s[vswz(d, kvg >> 1) + vsub] = w;
            }
        }
        __syncthreads();
        if (it + 1 < nt) {
            const int kb2 = kb + 64;
            #pragma unroll
            for (int i = 0; i < 4; i++) {
                kreg[i] = *(const uint4*)&K[bhoff + (size_t)(kb2 + krow + 16 * i) * HD_DIM + kd0];
                vreg[i] = *(const uint4*)&V[bhoff + (size_t)(kb2 + kvg * 4 + i) * HD_DIM + dg * 8];
            }
        }

        f32x4 s[4];
        #pragma unroll
        for (int f = 0; f < 4; f++) s[f] = (f32x4){0.f, 0.f, 0.f, 0.f};
        __builtin_amdgcn_s_setprio(1);
        #pragma unroll
        for (int kc = 0; kc < 4; kc++) {
            #pragma unroll
            for (int f = 0; f < 4; f++) {
                const bf16x8 kf = *(bf16x8*)&k_s[(f * 16 + m16) * 136 + kc * 32 + quad * 8];
                s[f] = __builtin_amdgcn_mfma_f32_16x16x32_bf16(qf[kc], kf, s[f], 0, 0, 0);
            }
        }
        __builtin_amdgcn_s_setprio(0);

        f32x4 mx;
        #pragma unroll
        for (int r = 0; r < 4; r++) {
            float m0 = -1e30f;
            #pragma unroll
            for (int f = 0; f < 4; f++) {
                float a = s[f][r] * scale;
                if (kb + f * 16 + m16 > row_g0 + r) a = -1e30f;
                s[f][r] = a;
                m0 = fmaxf(m0, a);
            }
            mx[r] = m0;
        }
        #pragma unroll
        for (int d = 1; d <= 8; d <<= 1)
            #pragma unroll
            for (int r = 0; r < 4; r++) mx[r] = fmaxf(mx[r], __shfl_xor(mx[r], d));

        f32x4 alpha, rs;
        #pragma unroll
        for (int r = 0; r < 4; r++) {
            const float mn = fmaxf(m_i[r], mx[r]);
            alpha[r] = __expf(m_i[r] - mn);
            m_i[r] = mn;
            float acc = 0.f;
            #pragma unroll
            for (int f = 0; f < 4; f++) {
                s[f][r] = __expf(s[f][r] - mn);
                acc += s[f][r];
            }
            rs[r] = acc;
        }
        #pragma unroll
        for (int d = 1; d <= 8; d <<= 1)
            #pragma unroll
            for (int r = 0; r < 4; r++) rs[r] += __shfl_xor(rs[r], d);
        #pragma unroll
        for (int r = 0; r < 4; r++) l_i[r] = l_i[r] * alpha[r] + rs[r];

        #pragma unroll
        for (int f = 0; f < 4; f++)
            #pragma unroll
            for (int r = 0; r < 4; r++)
                p_s[(wave * 16 + quad * 4 + r) * 72 + f * 16 + m16] = f2bf(s[f][r]);

        #pragma unroll
        for (int n = 0; n < 8; n++) o[n] *= alpha;

        __builtin_amdgcn_s_setprio(1);
        #pragma unroll
        for (int kc = 0; kc < 2; kc++) {
            const bf16x8 pa = *(bf16x8*)&p_s[(wave * 16 + m16) * 72 + kc * 32 + quad * 8];
            #pragma unroll
            for (int n = 0; n < 8; n++) {
                const int d = n * 16 + m16;
                const bf16x8 vb = *(bf16x8*)&v_s[vswz(d, kc * 4 + quad)];
                o[n] = __builtin_amdgcn_mfma_f32_16x16x32_bf16(pa, vb, o[n], 0, 0, 0);
            }
        }
        __builtin_amdgcn_s_setprio(0);
    }

    f32x4 inv;
    #pragma unroll
    for (int r = 0; r < 4; r++) inv[r] = 1.f / l_i[r];
    #pragma unroll
    for (int n = 0; n < 8; n++)
        #pragma unroll
        for (int r = 0; r < 4; r++)
            Out[bhoff + (size_t)(row_g0 + r) * HD_DIM + n * 16 + m16] =
                f2bf(o[n][r] * inv[r]);
}

// ---------- flash v4: 8 waves, QBLK=128, KVBLK=64 ----------
// Staging (32KB/tile + 2 barriers) amortized over 2x q-rows; Q fragments
// loaded directly from global (read once); skip-mask fast path for fully
// unmasked tiles. LDS: k_s 17408 + v_s 18432 + p_s 18432 = 54272 -> 2 blk/CU.
__global__ __launch_bounds__(512, 4) void flash_mfma8(const u16* __restrict__ Q,
                                                      const u16* __restrict__ K,
                                                      const u16* __restrict__ V,
                                                      u16* __restrict__ Out) {
    __shared__ __align__(16) u16 k_s[64 * 136];
    __shared__ __align__(16) u16 v_s[128 * 72];
    __shared__ __align__(16) u16 p_s[128 * 72];
    const int t = threadIdx.x;           // 0..511
    const int wave = t >> 6, lane = t & 63;
    const int quad = lane >> 4, m16 = lane & 15;
    const int h = blockIdx.y, b = blockIdx.z;
    const int q0 = (int)(gridDim.x - 1 - blockIdx.x) << 7;   // longest-first
    const size_t bhoff = ((size_t)(b * NHEAD + h)) * S_LEN * HD_DIM;

    // Q fragments direct from global (A-operand: row=m16, k=quad*8; same
    // formula as the validated LDS read in flash_mfma).
    bf16x8 qf[4];
    {
        const size_t qrow = bhoff + (size_t)(q0 + wave * 16 + m16) * HD_DIM;
        #pragma unroll
        for (int kc = 0; kc < 4; kc++)
            qf[kc] = *(const bf16x8*)&Q[qrow + kc * 32 + quad * 8];
    }

    f32x4 o[8];
    #pragma unroll
    for (int i = 0; i < 8; i++) o[i] = (f32x4){0.f, 0.f, 0.f, 0.f};
    f32x4 m_i = {-1e30f, -1e30f, -1e30f, -1e30f};
    f32x4 l_i = {0.f, 0.f, 0.f, 0.f};

    const int row_g0 = q0 + wave * 16 + quad * 4;
    const float scale = 0.08838834764831843f;
    const int nt = (q0 >> 6) + 2;        // kv tiles to cover rows q0..q0+127

    // staging lane assignments (512 threads)
    const int krow = t >> 4, kd0 = (t & 15) << 3;  // K: rows krow, krow+32
    const int dg = t & 15, kvp = t >> 4;           // V: rows kvp*2, kvp*2+1; d dg*8..+7
    const int vbase = (kvp & 3) << 1;              // u16 offset within 8-block

    uint4 kreg[2], vreg[2];
    kreg[0] = *(const uint4*)&K[bhoff + (size_t)(krow) * HD_DIM + kd0];
    kreg[1] = *(const uint4*)&K[bhoff + (size_t)(krow + 32) * HD_DIM + kd0];
    vreg[0] = *(const uint4*)&V[bhoff + (size_t)(kvp * 2) * HD_DIM + dg * 8];
    vreg[1] = *(const uint4*)&V[bhoff + (size_t)(kvp * 2 + 1) * HD_DIM + dg * 8];

    for (int it = 0; it < nt; ++it) {
        const int kb = it << 6;
        __syncthreads();   // previous iteration's LDS reads done
        *(uint4*)&k_s[(krow) * 136 + kd0]      = kreg[0];
        *(uint4*)&k_s[(krow + 32) * 136 + kd0] = kreg[1];
        {
            const u16* v0 = (const u16*)&vreg[0];
            const u16* v1 = (const u16*)&vreg[1];
            #pragma unroll
            for (int j = 0; j < 8; j++) {
                const int d = dg * 8 + j;
                const u32 w = (u32)v0[j] | ((u32)v1[j] << 16);
                *(u32*)&v_s[vswz(d, kvp >> 2) + vbase] = w;
            }
        }
        __syncthreads();
        if (it + 1 < nt) {
            const int kb2 = kb + 64;
            kreg[0] = *(const uint4*)&K[bhoff + (size_t)(kb2 + krow) * HD_DIM + kd0];
            kreg[1] = *(const uint4*)&K[bhoff + (size_t)(kb2 + krow + 32) * HD_DIM + kd0];
            vreg[0] = *(const uint4*)&V[bhoff + (size_t)(kb2 + kvp * 2) * HD_DIM + dg * 8];
            vreg[1] = *(const uint4*)&V[bhoff + (size_t)(kb2 + kvp * 2 + 1) * HD_DIM + dg * 8];
        }

        // ---- QK^T: 16 q-rows x 64 kv per wave ----
        f32x4 s[4];
        #pragma unroll
        for (int f = 0; f < 4; f++) s[f] = (f32x4){0.f, 0.f, 0.f, 0.f};
        __builtin_amdgcn_s_setprio(1);
        #pragma unroll
        for (int kc = 0; kc < 4; kc++) {
            #pragma unroll
            for (int f = 0; f < 4; f++) {
                const bf16x8 kf = *(bf16x8*)&k_s[(f * 16 + m16) * 136 + kc * 32 + quad * 8];
                s[f] = __builtin_amdgcn_mfma_f32_16x16x32_bf16(qf[kc], kf, s[f], 0, 0, 0);
            }
        }
        __builtin_amdgcn_s_setprio(0);

        // ---- scale (+mask only when tile touches the diagonal) + max ----
        f32x4 mx;
        if (kb + 63 > row_g0) {
            #pragma unroll
            for (int r = 0; r < 4; r++) {
                float m0 = -1e30f;
                #pragma unroll
                for (int f = 0; f < 4; f++) {
                    float a = s[f][r] * scale;
                    if (kb + f * 16 + m16 > row_g0 + r) a = -1e30f;
                    s[f][r] = a;
                    m0 = fmaxf(m0, a);
                }
                mx[r] = m0;
            }
        } else {
            #pragma unroll
            for (int r = 0; r < 4; r++) {
                float m0 = -1e30f;
                #pragma unroll
                for (int f = 0; f < 4; f++) {
                    const float a = s[f][r] * scale;
                    s[f][r] = a;
                    m0 = fmaxf(m0, a);
                }
                mx[r] = m0;
            }
        }
        #pragma unroll
        for (int d = 1; d <= 8; d <<= 1)
            #pragma unroll
            for (int r = 0; r < 4; r++) mx[r] = fmaxf(mx[r], __shfl_xor(mx[r], d));

        f32x4 alpha, rs;
        #pragma unroll
        for (int r = 0; r < 4; r++) {
            const float mn = fmaxf(m_i[r], mx[r]);
            alpha[r] = __expf(m_i[r] - mn);
            m_i[r] = mn;
            float acc = 0.f;
            #pragma unroll
            for (int f = 0; f < 4; f++) {
                s[f][r] = __expf(s[f][r] - mn);
                acc += s[f][r];
            }
            rs[r] = acc;
        }
        #pragma unroll
        for (int d = 1; d <= 8; d <<= 1)
            #pragma unroll
            for (int r = 0; r < 4; r++) rs[r] += __shfl_xor(rs[r], d);
        #pragma unroll
        for (int r = 0; r < 4; r++) l_i[r] = l_i[r] * alpha[r] + rs[r];

        // P -> LDS (wave-local rows; no barrier needed)
        #pragma unroll
        for (int f = 0; f < 4; f++)
            #pragma unroll
            for (int r = 0; r < 4; r++)
                p_s[(wave * 16 + quad * 4 + r) * 72 + f * 16 + m16] = f2bf(s[f][r]);

        #pragma unroll
        for (int n = 0; n < 8; n++) o[n] *= alpha;

        // ---- PV ----
        __builtin_amdgcn_s_setprio(1);
        #pragma unroll
        for (int kc = 0; kc < 2; kc++) {
            const bf16x8 pa = *(bf16x8*)&p_s[(wave * 16 + m16) * 72 + kc * 32 + quad * 8];
            #pragma unroll
            for (int n = 0; n < 8; n++) {
                const int d = n * 16 + m16;
                const bf16x8 vb = *(bf16x8*)&v_s[vswz(d, kc * 4 + quad)];
                o[n] = __builtin_amdgcn_mfma_f32_16x16x32_bf16(pa, vb, o[n], 0, 0, 0);
            }
        }
        __builtin_amdgcn_s_setprio(0);
    }

    f32x4 inv;
    #pragma unroll
    for (int r = 0; r < 4; r++) inv[r] = 1.f / l_i[r];
    #pragma unroll
    for (int n = 0; n < 8; n++)
        #pragma unroll
        for (int r = 0; r < 4; r++)
            Out[bhoff + (size_t)(row_g0 + r) * HD_DIM + n * 16 + m16] =
                f2bf(o[n][r] * inv[r]);
}

// ---------- launch ----------
extern "C" void kernel_launch(void* const* d_in, const int* in_sizes, int n_in,
                              void* d_out, int out_size, void* d_ws, size_t ws_size,
                              hipStream_t stream) {
    float* outf = (float*)d_out;

    bool order_ok = (n_in == 11);
    if (order_ok) {
        const int expect[11] = {8388608, 8388608, 8388608, 4194304, 2048,
                                4194304, 2048, 4194304, 2048, 4194304, 2048};
        for (int i = 0; i < 11; i++) order_ok = order_ok && (in_sizes[i] == expect[i]);
    }
    if (!order_ok) {
        fill_k<<<dim3((out_size + 255) / 256), dim3(256), 0, stream>>>(outf, 50.f, out_size);
        return;
    }
    if (ws_size < (size_t)BSD * sizeof(u16)) {
        fill_k<<<dim3((out_size + 255) / 256), dim3(256), 0, stream>>>(outf, 25.f, out_size);
        return;
    }

    const void* queries = d_in[0];
    const void* keys    = d_in[1];
    const void* values  = d_in[2];
    const void* Wq = d_in[3]; const void* bq = d_in[4];
    const void* Wk = d_in[5]; const void* bk = d_in[6];
    const void* Wv = d_in[7]; const void* bv = d_in[8];
    const void* Wo = d_in[9]; const void* bo = d_in[10];

    const dim3 tb(256);
    const dim3 gr(16384, 2);

    const size_t wslot = (size_t)D_DIM * D_DIM * 2;               // 8.39 MB
    const size_t need_full  = (size_t)BSD * 8 + 3 * wslot;        // 92.3 MB (ws >= this, R4)

    if (ws_size >= need_full) {
        // FULL PATH: all-bf16 fused QKV GEMM (dbuf) + 8-wave flash.
        u16* Qb = (u16*)d_ws;
        u16* Kb = Qb + BSD;
        u16* Vb = Kb + BSD;
        u16* WT = Vb + BSD;
        u16* XV = WT + 3 * (size_t)D_DIM * D_DIM;
        u16* XQ = (u16*)d_out;
        u16* XK = XQ + BSD;

        const dim3 gc3(4096, 3);
        const dim3 gt3(32, 32, 3);
        const dim3 gt(32, 32);
        const dim3 gq(16, 32, 3);
        const dim3 gb(16, 32);
        const dim3 gf8(S_LEN / 128, NHEAD, 2);
        const dim3 tb8(512);

        conv3<<<gc3, tb, 0, stream>>>(queries, keys, values, XQ, XK, XV);
        transpose_all<<<gt3, tb, 0, stream>>>(Wq, Wk, Wv, WT);
        qkv_gemm_bf<<<gq, tb, 0, stream>>>(XQ, XK, XV, WT, bq, bk, bv, Qb, Kb, Vb);
        transpose_w<<<gt, tb, 0, stream>>>(Wo, WT);   // slot 0 dead after qkv
        rope_k<<<gr, tb, 0, stream>>>(Qb, Kb);
        flash_mfma8<<<gf8, tb8, 0, stream>>>(Qb, Kb, Vb, Qb);
        bt_gemm<1><<<gb, tb, 0, stream>>>(Qb, WT, bo, outf);   // over dead XQ/XK
        return;
    }

    u16* Qb = (u16*)d_ws;
    u16* Kb = (u16*)d_out;
    u16* Vb = Kb + BSD;
    const dim3 gf(S_LEN / 64, NHEAD, 2);

    const size_t need_r3 = (size_t)BSD * 2 + 3 * wslot;           // 41.9 MB
    const size_t need_r2 = (size_t)BSD * 2 + wslot;               // 25.2 MB

    if (ws_size >= need_r3) {
        u16* WT = Qb + BSD;
        const dim3 gt3(32, 32, 3);
        const dim3 gt(32, 32);
        const dim3 gq(16, 32, 3);
        const dim3 gb(16, 32);

        transpose_all<<<gt3, tb, 0, stream>>>(Wq, Wk, Wv, WT);
        qkv_gemm<<<gq, tb, 0, stream>>>(queries, keys, values, WT,
                                        bq, bk, bv, Qb, Kb, Vb);
        transpose_w<<<gt, tb, 0, stream>>>(Wo, WT);
        rope_k<<<gr, tb, 0, stream>>>(Qb, Kb);
        flash_mfma<<<gf, tb, 0, stream>>>(Qb, Kb, Vb, Qb);
        bt_gemm<1><<<gb, tb, 0, stream>>>(Qb, WT, bo, outf);
    } else if (ws_size >= need_r2) {
        u16* WT = Qb + BSD;
        u16* XQ = Kb;
        u16* XK = Vb;
        const dim3 gt(32, 32);
        const dim3 gb(16, 32);
        const dim3 gc(4096);

        conv_bf16<<<gc, tb, 0, stream>>>(queries, XQ);
        conv_bf16<<<gc, tb, 0, stream>>>(keys, XK);

        transpose_w<<<gt, tb, 0, stream>>>(Wq, WT);
        bt_gemm<2><<<gb, tb, 0, stream>>>(XQ, WT, bq, Qb);
        transpose_w<<<gt, tb, 0, stream>>>(Wk, WT);
        bt_gemm<2><<<gb, tb, 0, stream>>>(XK, WT, bk, Kb);
        transpose_w<<<gt, tb, 0, stream>>>(Wv, WT);
        bt_gemm<0><<<gb, tb, 0, stream>>>(values, WT, bv, Vb);

        rope_k<<<gr, tb, 0, stream>>>(Qb, Kb);
        flash_mfma<<<gf, tb, 0, stream>>>(Qb, Kb, Vb, Qb);

        transpose_w<<<gt, tb, 0, stream>>>(Wo, WT);
        bt_gemm<1><<<gb, tb, 0, stream>>>(Qb, WT, bo, outf);
    } else {
        const dim3 gg(32, 64);
        gemm_qkv<<<gg, tb, 0, stream>>>(queries, Wq, bq, Qb);
        gemm_qkv<<<gg, tb, 0, stream>>>(keys,    Wk, bk, Kb);
        gemm_qkv<<<gg, tb, 0, stream>>>(values,  Wv, bv, Vb);
        rope_k<<<gr, tb, 0, stream>>>(Qb, Kb);
        flash_mfma<<<gf, tb, 0, stream>>>(Qb, Kb, Vb, Qb);
        gemm_o<<<gg, tb, 0, stream>>>(Qb, Wo, bo, outf);
    }
}

// Round 6
// 782.120 us; speedup vs baseline: 1.0758x; 1.0758x over previous
//
#include <hip/hip_runtime.h>
#include <hip/hip_bf16.h>
#include <math.h>

#define S_LEN 2048
#define D_DIM 2048
#define NHEAD 16
#define HD_DIM 128
#define NROWS 4096   // B*S
#define BSD 8388608  // NROWS*D_DIM elements (16.78 MB as bf16)

typedef __bf16 bf16x8 __attribute__((ext_vector_type(8)));
typedef float f32x4 __attribute__((ext_vector_type(4)));
typedef unsigned short u16;
typedef unsigned int u32;

__device__ __forceinline__ float bf2f(u16 h) {
    union { u32 u; float f; } v; v.u = ((u32)h) << 16; return v.f;
}
__device__ __forceinline__ u16 f2bf(float f) {
    union { float f; u32 u; } v; v.f = f;
    u32 r = v.u + 0x7fffu + ((v.u >> 16) & 1u);
    return (u16)(r >> 16);
}

// async global->LDS, 16B per lane
__device__ __forceinline__ void gld16(const void* g, void* l) {
    __builtin_amdgcn_global_load_lds((const __attribute__((address_space(1))) void*)g,
                                     (__attribute__((address_space(3))) void*)l,
                                     16, 0, 0);
}

// Dtype sniff (validated R5/R6: fires f32 on this harness).
__device__ __forceinline__ bool detect_f32(const void* p) {
    const u16* h = (const u16*)p;
    int sane = 0;
    for (int i = 0; i < 128; i++) {
        const u16 v = h[2 * i];
        const int e = (v >> 7) & 0xFF;
        sane += (int)((e >= 96 && e <= 150) || ((v & 0x7FFF) == 0));
    }
    return sane < 64;
}

__device__ __forceinline__ bf16x8 load8(const void* X, size_t eidx, bool f32) {
    if (!f32) return *(const bf16x8*)((const u16*)X + eidx);
    const float* xf = (const float*)X + eidx;
    const f32x4 a = *(const f32x4*)xf;
    const f32x4 b = *(const f32x4*)(xf + 4);
    bf16x8 r;
    u16* rp = (u16*)&r;
    rp[0] = f2bf(a[0]); rp[1] = f2bf(a[1]); rp[2] = f2bf(a[2]); rp[3] = f2bf(a[3]);
    rp[4] = f2bf(b[0]); rp[5] = f2bf(b[1]); rp[6] = f2bf(b[2]); rp[7] = f2bf(b[3]);
    return r;
}

__device__ __forceinline__ float bload(const void* b, int i, bool f32) {
    return f32 ? ((const float*)b)[i] : bf2f(((const u16*)b)[i]);
}

// ---------- diagnostic fill ----------
__global__ __launch_bounds__(256) void fill_k(float* __restrict__ out, float v, int n) {
    const int i = blockIdx.x * 256 + threadIdx.x;
    if (i < n) out[i] = v;
}

// ---------- activation f32 -> bf16 (or bf16 copy), 8 elems/thread ----------
__device__ __forceinline__ void conv_body(const void* __restrict__ in,
                                          u16* __restrict__ out, bool f32) {
    const size_t i = ((size_t)blockIdx.x * 256 + threadIdx.x) << 3;
    if (f32) {
        const f32x4 a = *(const f32x4*)((const float*)in + i);
        const f32x4 b = *(const f32x4*)((const float*)in + i + 4);
        uint4 w;
        w.x = (u32)f2bf(a[0]) | ((u32)f2bf(a[1]) << 16);
        w.y = (u32)f2bf(a[2]) | ((u32)f2bf(a[3]) << 16);
        w.z = (u32)f2bf(b[0]) | ((u32)f2bf(b[1]) << 16);
        w.w = (u32)f2bf(b[2]) | ((u32)f2bf(b[3]) << 16);
        *(uint4*)&out[i] = w;
    } else {
        *(uint4*)&out[i] = *(const uint4*)&((const u16*)in)[i];
    }
}

__global__ __launch_bounds__(256) void conv_bf16(const void* __restrict__ in,
                                                 u16* __restrict__ out) {
    conv_body(in, out, detect_f32(in));
}

// fused 3-stream conversion: y selects q/k/v
__global__ __launch_bounds__(256) void conv3(const void* __restrict__ q,
                                             const void* __restrict__ k,
                                             const void* __restrict__ v,
                                             u16* __restrict__ oq,
                                             u16* __restrict__ ok,
                                             u16* __restrict__ ov) {
    const int z = blockIdx.y;
    const void* in = (z == 0) ? q : (z == 1) ? k : v;
    u16* out = (z == 0) ? oq : (z == 1) ? ok : ov;
    conv_body(in, out, detect_f32(in));
}

// ---------- W transpose helper (device): [K,N] tile -> bf16 [N,K] ----------
__device__ __forceinline__ void transpose_body(const void* __restrict__ W,
                                               u16* __restrict__ out) {
    __shared__ float tile[64][68];
    const bool f32w = detect_f32(W);
    const int t = threadIdx.x;
    const int r = t >> 4, c4 = (t & 15) << 2;
    const int kb = blockIdx.y << 6, nb = blockIdx.x << 6;
    if (f32w) {
        #pragma unroll
        for (int i = 0; i < 4; i++) {
            const f32x4 v = *(const f32x4*)((const float*)W +
                (size_t)(kb + r + 16 * i) * D_DIM + nb + c4);
            tile[r + 16 * i][c4 + 0] = v[0];
            tile[r + 16 * i][c4 + 1] = v[1];
            tile[r + 16 * i][c4 + 2] = v[2];
            tile[r + 16 * i][c4 + 3] = v[3];
        }
    } else {
        #pragma unroll
        for (int i = 0; i < 4; i++)
            #pragma unroll
            for (int j = 0; j < 4; j++)
                tile[r + 16 * i][c4 + j] =
                    bf2f(((const u16*)W)[(size_t)(kb + r + 16 * i) * D_DIM + nb + c4 + j]);
    }
    __syncthreads();
    #pragma unroll
    for (int i = 0; i < 4; i++) {
        const int n = nb + r + 16 * i;
        u16 pk[4];
        #pragma unroll
        for (int j = 0; j < 4; j++) pk[j] = f2bf(tile[c4 + j][r + 16 * i]);
        *(uint2*)&out[(size_t)n * D_DIM + kb + c4] = *(uint2*)pk;
    }
}

__global__ __launch_bounds__(256) void transpose_w(const void* __restrict__ W,
                                                   u16* __restrict__ out) {
    transpose_body(W, out);
}

// fused: z selects Wq/Wk/Wv -> slot z
__global__ __launch_bounds__(256) void transpose_all(const void* __restrict__ W0,
                                                     const void* __restrict__ W1,
                                                     const void* __restrict__ W2,
                                                     u16* __restrict__ out) {
    const int z = blockIdx.z;
    const void* W = (z == 0) ? W0 : (z == 1) ? W1 : W2;
    transpose_body(W, out + (size_t)z * D_DIM * D_DIM);
}

// ---------- fused QKV GEMM, all-bf16, single-barrier dbuf ----------
__global__ __launch_bounds__(256) void qkv_gemm_bf(const u16* __restrict__ Xq,
                                                   const u16* __restrict__ Xk,
                                                   const u16* __restrict__ Xv,
                                                   const u16* __restrict__ WTbase,
                                                   const void* __restrict__ bqp,
                                                   const void* __restrict__ bkp,
                                                   const void* __restrict__ bvp,
                                                   u16* __restrict__ Oq,
                                                   u16* __restrict__ Ok,
                                                   u16* __restrict__ Ov) {
    __shared__ __align__(16) u16 a_s[2][128 * 32];
    __shared__ __align__(16) u16 b_s[2][128 * 32];
    const int z = blockIdx.z;
    const u16* X    = (z == 0) ? Xq  : (z == 1) ? Xk  : Xv;
    const void* bias= (z == 0) ? bqp : (z == 1) ? bkp : bvp;
    u16* out        = (z == 0) ? Oq  : (z == 1) ? Ok  : Ov;
    const u16* WT   = WTbase + (size_t)z * D_DIM * D_DIM;
    const bool f32b = detect_f32(bias);
    const int t = threadIdx.x;
    const int wave = t >> 6, lane = t & 63;
    const int quad = lane >> 4, m16 = lane & 15;
    const int wm = (wave >> 1) << 6, wn = (wave & 1) << 6;
    const int rowBase = blockIdx.y << 7, colBase = blockIdx.x << 7;
    const int arow = t >> 2, aoff = (t & 3) << 3;

    f32x4 acc[4][4];
    #pragma unroll
    for (int i = 0; i < 4; i++)
        #pragma unroll
        for (int j = 0; j < 4; j++) acc[i][j] = (f32x4){0.f, 0.f, 0.f, 0.f};

    gld16(&X[(size_t)(rowBase + arow) * D_DIM + aoff],        &a_s[0][t * 8]);
    gld16(&X[(size_t)(rowBase + arow + 64) * D_DIM + aoff],   &a_s[0][(t + 256) * 8]);
    gld16(&WT[(size_t)(colBase + arow) * D_DIM + aoff],       &b_s[0][t * 8]);
    gld16(&WT[(size_t)(colBase + arow + 64) * D_DIM + aoff],  &b_s[0][(t + 256) * 8]);
    __syncthreads();

    int cur = 0;
    for (int k0 = 0; k0 < D_DIM; k0 += 32, cur ^= 1) {
        if (k0 + 32 < D_DIM) {
            const int kn = k0 + 32;
            gld16(&X[(size_t)(rowBase + arow) * D_DIM + kn + aoff],       &a_s[cur ^ 1][t * 8]);
            gld16(&X[(size_t)(rowBase + arow + 64) * D_DIM + kn + aoff],  &a_s[cur ^ 1][(t + 256) * 8]);
            gld16(&WT[(size_t)(colBase + arow) * D_DIM + kn + aoff],      &b_s[cur ^ 1][t * 8]);
            gld16(&WT[(size_t)(colBase + arow + 64) * D_DIM + kn + aoff], &b_s[cur ^ 1][(t + 256) * 8]);
        }
        bf16x8 af[4], bfr[4];
        #pragma unroll
        for (int mi = 0; mi < 4; mi++)
            af[mi] = *(bf16x8*)&a_s[cur][(wm + mi * 16 + m16) * 32 + quad * 8];
        #pragma unroll
        for (int ni = 0; ni < 4; ni++)
            bfr[ni] = *(bf16x8*)&b_s[cur][(wn + ni * 16 + m16) * 32 + quad * 8];
        #pragma unroll
        for (int mi = 0; mi < 4; mi++)
            #pragma unroll
            for (int ni = 0; ni < 4; ni++)
                acc[mi][ni] = __builtin_amdgcn_mfma_f32_16x16x32_bf16(
                    af[mi], bfr[ni], acc[mi][ni], 0, 0, 0);
        __syncthreads();
    }

    #pragma unroll
    for (int ni = 0; ni < 4; ni++) {
        const int col = colBase + wn + ni * 16 + m16;
        const float bv = bload(bias, col, f32b);
        const int h = col >> 7, hd = col & (HD_DIM - 1);
        #pragma unroll
        for (int mi = 0; mi < 4; mi++) {
            #pragma unroll
            for (int r = 0; r < 4; r++) {
                const int row = rowBase + wm + mi * 16 + quad * 4 + r;
                const int b = row >> 11, s = row & (S_LEN - 1);
                out[(((size_t)(b * NHEAD + h)) * S_LEN + s) * HD_DIM + hd] =
                    f2bf(acc[mi][ni][r] + bv);
            }
        }
    }
}

// ---------- fused QKV GEMM, f32 A (R3-validated; mid-tier ws fallback) ----------
__global__ __launch_bounds__(256) void qkv_gemm(const void* __restrict__ Xq,
                                                const void* __restrict__ Xk,
                                                const void* __restrict__ Xv,
                                                const u16* __restrict__ WTbase,
                                                const void* __restrict__ bqp,
                                                const void* __restrict__ bkp,
                                                const void* __restrict__ bvp,
                                                u16* __restrict__ Oq,
                                                u16* __restrict__ Ok,
                                                u16* __restrict__ Ov) {
    __shared__ __align__(16) u16 a_s[128 * 32];
    __shared__ __align__(16) u16 b_s[128 * 32];
    const int z = blockIdx.z;
    const void* X   = (z == 0) ? Xq  : (z == 1) ? Xk  : Xv;
    const void* bias= (z == 0) ? bqp : (z == 1) ? bkp : bvp;
    u16* out        = (z == 0) ? Oq  : (z == 1) ? Ok  : Ov;
    const u16* WT   = WTbase + (size_t)z * D_DIM * D_DIM;
    const bool f32x = detect_f32(X);
    const bool f32b = detect_f32(bias);
    const int t = threadIdx.x;
    const int wave = t >> 6, lane = t & 63;
    const int quad = lane >> 4, m16 = lane & 15;
    const int wm = (wave >> 1) << 6, wn = (wave & 1) << 6;
    const int rowBase = blockIdx.y << 7, colBase = blockIdx.x << 7;
    const int arow = t >> 2, aoff = (t & 3) << 3;

    f32x4 acc[4][4];
    #pragma unroll
    for (int i = 0; i < 4; i++)
        #pragma unroll
        for (int j = 0; j < 4; j++) acc[i][j] = (f32x4){0.f, 0.f, 0.f, 0.f};

    for (int k0 = 0; k0 < D_DIM; k0 += 32) {
        const bf16x8 av0 = load8(X, (size_t)(rowBase + arow) * D_DIM + k0 + aoff, f32x);
        const bf16x8 av1 = load8(X, (size_t)(rowBase + arow + 64) * D_DIM + k0 + aoff, f32x);
        __syncthreads();
        *(bf16x8*)&a_s[arow * 32 + aoff]        = av0;
        *(bf16x8*)&a_s[(arow + 64) * 32 + aoff] = av1;
        gld16(&WT[(size_t)(colBase + arow) * D_DIM + k0 + aoff],      &b_s[t * 8]);
        gld16(&WT[(size_t)(colBase + arow + 64) * D_DIM + k0 + aoff], &b_s[(t + 256) * 8]);
        __syncthreads();

        bf16x8 af[4], bfr[4];
        #pragma unroll
        for (int mi = 0; mi < 4; mi++)
            af[mi] = *(bf16x8*)&a_s[(wm + mi * 16 + m16) * 32 + quad * 8];
        #pragma unroll
        for (int ni = 0; ni < 4; ni++)
            bfr[ni] = *(bf16x8*)&b_s[(wn + ni * 16 + m16) * 32 + quad * 8];
        #pragma unroll
        for (int mi = 0; mi < 4; mi++)
            #pragma unroll
            for (int ni = 0; ni < 4; ni++)
                acc[mi][ni] = __builtin_amdgcn_mfma_f32_16x16x32_bf16(
                    af[mi], bfr[ni], acc[mi][ni], 0, 0, 0);
    }

    #pragma unroll
    for (int ni = 0; ni < 4; ni++) {
        const int col = colBase + wn + ni * 16 + m16;
        const float bv = bload(bias, col, f32b);
        const int h = col >> 7, hd = col & (HD_DIM - 1);
        #pragma unroll
        for (int mi = 0; mi < 4; mi++) {
            #pragma unroll
            for (int r = 0; r < 4; r++) {
                const int row = rowBase + wm + mi * 16 + quad * 4 + r;
                const int b = row >> 11, s = row & (S_LEN - 1);
                out[(((size_t)(b * NHEAD + h)) * S_LEN + s) * HD_DIM + hd] =
                    f2bf(acc[mi][ni][r] + bv);
            }
        }
    }
}

// ---------- 128x128-tile GEMM vs pre-transposed bf16 WT [N,K] ----------
template<int MODE>
__global__ __launch_bounds__(256) void bt_gemm(const void* __restrict__ X,
                                               const u16* __restrict__ WT,
                                               const void* __restrict__ bias,
                                               void* __restrict__ out) {
    const bool f32b = detect_f32(bias);
    const int t = threadIdx.x;
    const int wave = t >> 6, lane = t & 63;
    const int quad = lane >> 4, m16 = lane & 15;
    const int wm = (wave >> 1) << 6, wn = (wave & 1) << 6;
    const int rowBase = blockIdx.y << 7, colBase = blockIdx.x << 7;
    const int arow = t >> 2, aoff = (t & 3) << 3;

    f32x4 acc[4][4];
    #pragma unroll
    for (int i = 0; i < 4; i++)
        #pragma unroll
        for (int j = 0; j < 4; j++) acc[i][j] = (f32x4){0.f, 0.f, 0.f, 0.f};

    if constexpr (MODE == 0) {
        __shared__ __align__(16) u16 a_s[128 * 32];
        __shared__ __align__(16) u16 b_s[128 * 32];
        const bool f32x = detect_f32(X);
        for (int k0 = 0; k0 < D_DIM; k0 += 32) {
            const bf16x8 av0 = load8(X, (size_t)(rowBase + arow) * D_DIM + k0 + aoff, f32x);
            const bf16x8 av1 = load8(X, (size_t)(rowBase + arow + 64) * D_DIM + k0 + aoff, f32x);
            __syncthreads();
            *(bf16x8*)&a_s[arow * 32 + aoff]        = av0;
            *(bf16x8*)&a_s[(arow + 64) * 32 + aoff] = av1;
            gld16(&WT[(size_t)(colBase + arow) * D_DIM + k0 + aoff],      &b_s[t * 8]);
            gld16(&WT[(size_t)(colBase + arow + 64) * D_DIM + k0 + aoff], &b_s[(t + 256) * 8]);
            __syncthreads();

            bf16x8 af[4], bfr[4];
            #pragma unroll
            for (int mi = 0; mi < 4; mi++)
                af[mi] = *(bf16x8*)&a_s[(wm + mi * 16 + m16) * 32 + quad * 8];
            #pragma unroll
            for (int ni = 0; ni < 4; ni++)
                bfr[ni] = *(bf16x8*)&b_s[(wn + ni * 16 + m16) * 32 + quad * 8];
            #pragma unroll
            for (int mi = 0; mi < 4; mi++)
                #pragma unroll
                for (int ni = 0; ni < 4; ni++)
                    acc[mi][ni] = __builtin_amdgcn_mfma_f32_16x16x32_bf16(
                        af[mi], bfr[ni], acc[mi][ni], 0, 0, 0);
        }
    } else {
        __shared__ __align__(16) u16 a_s[2][128 * 32];
        __shared__ __align__(16) u16 b_s[2][128 * 32];
        #define STAGE_T(buf, kk)                                                          \
            do {                                                                          \
                if (MODE == 2) {                                                          \
                    gld16(&((const u16*)X)[(size_t)(rowBase + arow) * D_DIM + (kk) + aoff],      \
                          &a_s[buf][t * 8]);                                              \
                    gld16(&((const u16*)X)[(size_t)(rowBase + arow + 64) * D_DIM + (kk) + aoff], \
                          &a_s[buf][(t + 256) * 8]);                                      \
                } else {                                                                  \
                    const int kg = (kk) + aoff, hh = kg >> 7, hd2 = kg & (HD_DIM - 1);    \
                    const int r0 = rowBase + arow, r1 = r0 + 64;                          \
                    gld16(&((const u16*)X)[                                               \
                        (((size_t)((r0 >> 11) * NHEAD + hh)) * S_LEN + (r0 & (S_LEN - 1))) * HD_DIM + hd2], \
                        &a_s[buf][t * 8]);                                                \
                    gld16(&((const u16*)X)[                                               \
                        (((size_t)((r1 >> 11) * NHEAD + hh)) * S_LEN + (r1 & (S_LEN - 1))) * HD_DIM + hd2], \
                        &a_s[buf][(t + 256) * 8]);                                        \
                }                                                                         \
                gld16(&WT[(size_t)(colBase + arow) * D_DIM + (kk) + aoff],      &b_s[buf][t * 8]);        \
                gld16(&WT[(size_t)(colBase + arow + 64) * D_DIM + (kk) + aoff], &b_s[buf][(t + 256) * 8]);\
            } while (0)

        STAGE_T(0, 0);
        __syncthreads();
        int cur = 0;
        for (int k0 = 0; k0 < D_DIM; k0 += 32, cur ^= 1) {
            if (k0 + 32 < D_DIM) STAGE_T(cur ^ 1, k0 + 32);
            bf16x8 af[4], bfr[4];
            #pragma unroll
            for (int mi = 0; mi < 4; mi++)
                af[mi] = *(bf16x8*)&a_s[cur][(wm + mi * 16 + m16) * 32 + quad * 8];
            #pragma unroll
            for (int ni = 0; ni < 4; ni++)
                bfr[ni] = *(bf16x8*)&b_s[cur][(wn + ni * 16 + m16) * 32 + quad * 8];
            #pragma unroll
            for (int mi = 0; mi < 4; mi++)
                #pragma unroll
                for (int ni = 0; ni < 4; ni++)
                    acc[mi][ni] = __builtin_amdgcn_mfma_f32_16x16x32_bf16(
                        af[mi], bfr[ni], acc[mi][ni], 0, 0, 0);
            __syncthreads();
        }
        #undef STAGE_T
    }

    #pragma unroll
    for (int ni = 0; ni < 4; ni++) {
        const int col = colBase + wn + ni * 16 + m16;
        const float bv = bload(bias, col, f32b);
        const int h = col >> 7, hd = col & (HD_DIM - 1);
        #pragma unroll
        for (int mi = 0; mi < 4; mi++) {
            #pragma unroll
            for (int r = 0; r < 4; r++) {
                const int row = rowBase + wm + mi * 16 + quad * 4 + r;
                const float v = acc[mi][ni][r] + bv;
                if (MODE == 1) {
                    ((float*)out)[(size_t)row * D_DIM + col] = v;
                } else {
                    const int b = row >> 11, s = row & (S_LEN - 1);
                    ((u16*)out)[(((size_t)(b * NHEAD + h)) * S_LEN + s) * HD_DIM + hd] = f2bf(v);
                }
            }
        }
    }
}

// ---------- FALLBACK 64-tile GEMMs (validated R6/R7; used if ws too small) ----------
__global__ __launch_bounds__(256) void gemm_qkv(const void* __restrict__ X,
                                                const void* __restrict__ W,
                                                const void* __restrict__ bias,
                                                u16* __restrict__ out) {
    __shared__ __align__(16) u16 a_s[64 * 32];
    __shared__ __align__(16) u16 b_s[64 * 40];
    const bool f32x = detect_f32(X);
    const bool f32w = detect_f32(W);
    const bool f32b = detect_f32(bias);
    const int t = threadIdx.x;
    const int wave = t >> 6, lane = t & 63;
    const int quad = lane >> 4, mrow = lane & 15;
    const int rowBase = blockIdx.y * 64;
    const int colBase = blockIdx.x * 64;
    const int srow = t >> 2, soff = (t & 3) << 3;
    const int krow = t >> 3, ncol0 = (t & 7) << 3;

    f32x4 acc0 = {0.f, 0.f, 0.f, 0.f};
    f32x4 acc1 = acc0, acc2 = acc0, acc3 = acc0;

    for (int k0 = 0; k0 < D_DIM; k0 += 32) {
        const bf16x8 av = load8(X, (size_t)(rowBase + srow) * D_DIM + k0 + soff, f32x);
        const bf16x8 wv = load8(W, (size_t)(k0 + krow) * D_DIM + colBase + ncol0, f32w);
        __syncthreads();
        *(bf16x8*)&a_s[srow * 32 + soff] = av;
        const u16* wp = (const u16*)&wv;
        #pragma unroll
        for (int j = 0; j < 8; j++) b_s[(ncol0 + j) * 40 + krow] = wp[j];
        __syncthreads();
        const bf16x8 af  = *(bf16x8*)&a_s[(wave * 16 + mrow) * 32 + (quad << 3)];
        const bf16x8 bf0 = *(bf16x8*)&b_s[(     mrow) * 40 + (quad << 3)];
        const bf16x8 bf1 = *(bf16x8*)&b_s[(16 + mrow) * 40 + (quad << 3)];
        const bf16x8 bf2 = *(bf16x8*)&b_s[(32 + mrow) * 40 + (quad << 3)];
        const bf16x8 bf3 = *(bf16x8*)&b_s[(48 + mrow) * 40 + (quad << 3)];
        acc0 = __builtin_amdgcn_mfma_f32_16x16x32_bf16(af, bf0, acc0, 0, 0, 0);
        acc1 = __builtin_amdgcn_mfma_f32_16x16x32_bf16(af, bf1, acc1, 0, 0, 0);
        acc2 = __builtin_amdgcn_mfma_f32_16x16x32_bf16(af, bf2, acc2, 0, 0, 0);
        acc3 = __builtin_amdgcn_mfma_f32_16x16x32_bf16(af, bf3, acc3, 0, 0, 0);
    }

    const f32x4 accs[4] = {acc0, acc1, acc2, acc3};
    #pragma unroll
    for (int cb = 0; cb < 4; cb++) {
        const int col = colBase + cb * 16 + mrow;
        const float bv = bload(bias, col, f32b);
        const int h = col >> 7, hd = col & (HD_DIM - 1);
        #pragma unroll
        for (int r = 0; r < 4; r++) {
            const int row = rowBase + wave * 16 + quad * 4 + r;
            const int b = row >> 11, s = row & (S_LEN - 1);
            out[(((size_t)(b * NHEAD + h)) * S_LEN + s) * HD_DIM + hd] =
                f2bf(accs[cb][r] + bv);
        }
    }
}

__global__ __launch_bounds__(256) void gemm_o(const u16* __restrict__ A,
                                              const void* __restrict__ W,
                                              const void* __restrict__ bias,
                                              float* __restrict__ out) {
    __shared__ __align__(16) u16 a_s[64 * 32];
    __shared__ __align__(16) u16 b_s[64 * 40];
    const bool f32w = detect_f32(W);
    const bool f32b = detect_f32(bias);
    const int t = threadIdx.x;
    const int wave = t >> 6, lane = t & 63;
    const int quad = lane >> 4, mrow = lane & 15;
    const int rowBase = blockIdx.y * 64;
    const int colBase = blockIdx.x * 64;
    const int srow = t >> 2, soff = (t & 3) << 3;
    const int krow = t >> 3, ncol0 = (t & 7) << 3;

    f32x4 acc0 = {0.f, 0.f, 0.f, 0.f};
    f32x4 acc1 = acc0, acc2 = acc0, acc3 = acc0;

    const int row = rowBase + srow;
    const int rb = row >> 11, rs = row & (S_LEN - 1);

    for (int k0 = 0; k0 < D_DIM; k0 += 32) {
        const int kg = k0 + soff;
        const int h = kg >> 7, hd = kg & (HD_DIM - 1);
        const bf16x8 av = *(const bf16x8*)&A[
            (((size_t)(rb * NHEAD + h)) * S_LEN + rs) * HD_DIM + hd];
        const bf16x8 wv = load8(W, (size_t)(k0 + krow) * D_DIM + colBase + ncol0, f32w);
        __syncthreads();
        *(bf16x8*)&a_s[srow * 32 + soff] = av;
        const u16* wp = (const u16*)&wv;
        #pragma unroll
        for (int j = 0; j < 8; j++) b_s[(ncol0 + j) * 40 + krow] = wp[j];
        __syncthreads();
        const bf16x8 af  = *(bf16x8*)&a_s[(wave * 16 + mrow) * 32 + (quad << 3)];
        const bf16x8 bf0 = *(bf16x8*)&b_s[(     mrow) * 40 + (quad << 3)];
        const bf16x8 bf1 = *(bf16x8*)&b_s[(16 + mrow) * 40 + (quad << 3)];
        const bf16x8 bf2 = *(bf16x8*)&b_s[(32 + mrow) * 40 + (quad << 3)];
        const bf16x8 bf3 = *(bf16x8*)&b_s[(48 + mrow) * 40 + (quad << 3)];
        acc0 = __builtin_amdgcn_mfma_f32_16x16x32_bf16(af, bf0, acc0, 0, 0, 0);
        acc1 = __builtin_amdgcn_mfma_f32_16x16x32_bf16(af, bf1, acc1, 0, 0, 0);
        acc2 = __builtin_amdgcn_mfma_f32_16x16x32_bf16(af, bf2, acc2, 0, 0, 0);
        acc3 = __builtin_amdgcn_mfma_f32_16x16x32_bf16(af, bf3, acc3, 0, 0, 0);
    }

    const f32x4 accs[4] = {acc0, acc1, acc2, acc3};
    #pragma unroll
    for (int cb = 0; cb < 4; cb++) {
        const int col = colBase + cb * 16 + mrow;
        const float bv = bload(bias, col, f32b);
        #pragma unroll
        for (int r = 0; r < 4; r++) {
            const int orow = rowBase + wave * 16 + quad * 4 + r;
            out[(size_t)orow * D_DIM + col] = accs[cb][r] + bv;
        }
    }
}

// ---------- RoPE in-place, [B,16,S,HD]; cos/sin fp32 ----------
__global__ __launch_bounds__(256) void rope_k(u16* __restrict__ q, u16* __restrict__ k) {
    const int idx = blockIdx.x * 256 + threadIdx.x;
    u16* p = blockIdx.y ? k : q;
    const int i  = idx & 63;
    const int s  = (idx >> 6) & (S_LEN - 1);
    const int bh = idx >> 17;
    const size_t base = ((size_t)bh * S_LEN + s) * HD_DIM;
    const float inv = __expf((float)i * -0.14391157f);
    const float ang = (float)s * inv;
    const float c = cosf(ang), sn = sinf(ang);
    const float x1 = bf2f(p[base + i]);
    const float x2 = bf2f(p[base + 64 + i]);
    p[base + i]      = f2bf(x1 * c - x2 * sn);
    p[base + 64 + i] = f2bf(x2 * c + x1 * sn);
}

// V^T LDS swizzle (validated R1): row d holds kv in 8-elem blocks permuted.
__device__ __forceinline__ int vswz(int d, int blk8) {
    return d * 72 + (((blk8) ^ ((d ^ (d >> 3)) & 7)) << 3);
}

// Weight-balanced causal q-tile mapping (R6). Dispatch c and c+nx*ny get the
// SAME blockIdx.x; with naive mapping both have equal iteration counts and a
// wrap-around CU assignment doubles the critical path (measured: occupancy
// 22.7%, flash invariant at ~230us across structures). Interleave long/short
// within consecutive x and complement across z so co-resident pairs sum to
// the mean. Bijective per z.
__device__ __forceinline__ int qtile_bal(int bx, int ntiles, int z) {
    const int m = bx >> 1;
    int qt = (bx & 1) ? m : (ntiles - 1 - m);
    if (z & 1) qt = ntiles - 1 - qt;
    return qt;
}

// ---------- flash v3 (validated R1/R2: 232 us) — fallback paths ----------
__global__ __launch_bounds__(256, 3) void flash_mfma(const u16* Q,
                                                     const u16* __restrict__ K,
                                                     const u16* __restrict__ V,
                                                     u16* Out) {
    __shared__ __align__(16) u16 k_s[64 * 136];
    __shared__ __align__(16) u16 v_s[128 * 72];
    __shared__ __align__(16) u16 p_s[64 * 72];
    const int t = threadIdx.x;
    const int wave = t >> 6, lane = t & 63;
    const int quad = lane >> 4, m16 = lane & 15;
    const int h = blockIdx.y, b = blockIdx.z;
    const int q0 = qtile_bal(blockIdx.x, gridDim.x, b) << 6;
    const size_t bhoff = ((size_t)(b * NHEAD + h)) * S_LEN * HD_DIM;

    #pragma unroll
    for (int i = 0; i < 4; i++) {
        const int chunk = t + 256 * i;
        const int row = chunk >> 4, d0 = (chunk & 15) << 3;
        *(uint4*)&k_s[row * 136 + d0] =
            *(const uint4*)&Q[bhoff + (size_t)(q0 + row) * HD_DIM + d0];
    }
    __syncthreads();
    bf16x8 qf[4];
    #pragma unroll
    for (int kc = 0; kc < 4; kc++)
        qf[kc] = *(bf16x8*)&k_s[(wave * 16 + m16) * 136 + kc * 32 + quad * 8];

    f32x4 o[8];
    #pragma unroll
    for (int i = 0; i < 8; i++) o[i] = (f32x4){0.f, 0.f, 0.f, 0.f};
    f32x4 m_i = {-1e30f, -1e30f, -1e30f, -1e30f};
    f32x4 l_i = {0.f, 0.f, 0.f, 0.f};

    const int row_g0 = q0 + wave * 16 + quad * 4;
    const float scale = 0.08838834764831843f;
    const int nt = (q0 >> 6) + 1;

    const int krow = t >> 4, kd0 = (t & 15) << 3;
    const int dg = t & 15, kvg = t >> 4;
    const int vsub = (kvg & 1) << 2;

    uint4 kreg[4], vreg[4];
    #pragma unroll
    for (int i = 0; i < 4; i++) {
        kreg[i] = *(const uint4*)&K[bhoff + (size_t)(krow + 16 * i) * HD_DIM + kd0];
        vreg[i] = *(const uint4*)&V[bhoff + (size_t)(kvg * 4 + i) * HD_DIM + dg * 8];
    }

    for (int it = 0; it < nt; ++it) {
        const int kb = it << 6;
        __syncthreads();
        #pragma unroll
        for (int i = 0; i < 4; i++)
            *(uint4*)&k_s[(krow + 16 * i) * 136 + kd0] = kreg[i];
        {
            const u16* v0 = (const u16*)&vreg[0];
            const u16* v1 = (const u16*)&vreg[1];
            const u16* v2 = (const u16*)&vreg[2];
            const u16* v3 = (const u16*)&vreg[3];
            #pragma unroll
            for (int j = 0; j < 8; j++) {
                const int d = dg * 8 + j;
                uint2 w;
                w.x = (u32)v0[j] | ((u32)v1[j] << 16);
                w.y = (u32)v2[j] | ((u32)v3[j] << 16);
                *(uint2*)&v_s[vswz(d, kvg >> 1) + vsub] = w;
            }
        }
        __syncthreads();
        if (it + 1 < nt) {
            const int kb2 = kb + 64;
            #pragma unroll
            for (int i = 0; i < 4; i++) {
                kreg[i] = *(const uint4*)&K[bhoff + (size_t)(kb2 + krow + 16 * i) * HD_DIM + kd0];
                vreg[i] = *(const uint4*)&V[bhoff + (size_t)(kb2 + kvg * 4 + i) * HD_DIM + dg * 8];
            }
        }

        f32x4 s[4];
        #pragma unroll
        for (int f = 0; f < 4; f++) s[f] = (f32x4){0.f, 0.f, 0.f, 0.f};
        __builtin_amdgcn_s_setprio(1);
        #pragma unroll
        for (int kc = 0; kc < 4; kc++) {
            #pragma unroll
            for (int f = 0; f < 4; f++) {
                const bf16x8 kf = *(bf16x8*)&k_s[(f * 16 + m16) * 136 + kc * 32 + quad * 8];
                s[f] = __builtin_amdgcn_mfma_f32_16x16x32_bf16(qf[kc], kf, s[f], 0, 0, 0);
            }
        }
        __builtin_amdgcn_s_setprio(0);

        f32x4 mx;
        #pragma unroll
        for (int r = 0; r < 4; r++) {
            float m0 = -1e30f;
            #pragma unroll
            for (int f = 0; f < 4; f++) {
                float a = s[f][r] * scale;
                if (kb + f * 16 + m16 > row_g0 + r) a = -1e30f;
                s[f][r] = a;
                m0 = fmaxf(m0, a);
            }
            mx[r] = m0;
        }
        #pragma unroll
        for (int d = 1; d <= 8; d <<= 1)
            #pragma unroll
            for (int r = 0; r < 4; r++) mx[r] = fmaxf(mx[r], __shfl_xor(mx[r], d));

        f32x4 alpha, rs;
        #pragma unroll
        for (int r = 0; r < 4; r++) {
            const float mn = fmaxf(m_i[r], mx[r]);
            alpha[r] = __expf(m_i[r] - mn);
            m_i[r] = mn;
            float acc = 0.f;
            #pragma unroll
            for (int f = 0; f < 4; f++) {
                s[f][r] = __expf(s[f][r] - mn);
                acc += s[f][r];
            }
            rs[r] = acc;
        }
        #pragma unroll
        for (int d = 1; d <= 8; d <<= 1)
            #pragma unroll
            for (int r = 0; r < 4; r++) rs[r] += __shfl_xor(rs[r], d);
        #pragma unroll
        for (int r = 0; r < 4; r++) l_i[r] = l_i[r] * alpha[r] + rs[r];

        #pragma unroll
        for (int f = 0; f < 4; f++)
            #pragma unroll
            for (int r = 0; r < 4; r++)
                p_s[(wave * 16 + quad * 4 + r) * 72 + f * 16 + m16] = f2bf(s[f][r]);

        #pragma unroll
        for (int n = 0; n < 8; n++) o[n] *= alpha;

        __builtin_amdgcn_s_setprio(1);
        #pragma unroll
        for (int kc = 0; kc < 2; kc++) {
            const bf16x8 pa = *(bf16x8*)&p_s[(wave * 16 + m16) * 72 + kc * 32 + quad * 8];
            #pragma unroll
            for (int n = 0; n < 8; n++) {
                const int d = n * 16 + m16;
                const bf16x8 vb = *(bf16x8*)&v_s[vswz(d, kc * 4 + quad)];
                o[n] = __builtin_amdgcn_mfma_f32_16x16x32_bf16(pa, vb, o[n], 0, 0, 0);
            }
        }
        __builtin_amdgcn_s_setprio(0);
    }

    f32x4 inv;
    #pragma unroll
    for (int r = 0; r < 4; r++) inv[r] = 1.f / l_i[r];
    #pragma unroll
    for (int n = 0; n < 8; n++)
        #pragma unroll
        for (int r = 0; r < 4; r++)
            Out[bhoff + (size_t)(row_g0 + r) * HD_DIM + n * 16 + m16] =
                f2bf(o[n][r] * inv[r]);
}

// ---------- flash v4: 8 waves, QBLK=128, KVBLK=64 (R5) + balanced mapping (R6) ----------
__global__ __launch_bounds__(512, 4) void flash_mfma8(const u16* __restrict__ Q,
                                                      const u16* __restrict__ K,
                                                      const u16* __restrict__ V,
                                                      u16* __restrict__ Out) {
    __shared__ __align__(16) u16 k_s[64 * 136];
    __shared__ __align__(16) u16 v_s[128 * 72];
    __shared__ __align__(16) u16 p_s[128 * 72];
    const int t = threadIdx.x;           // 0..511
    const int wave = t >> 6, lane = t & 63;
    const int quad = lane >> 4, m16 = lane & 15;
    const int h = blockIdx.y, b = blockIdx.z;
    const int q0 = qtile_bal(blockIdx.x, gridDim.x, b) << 7;
    const size_t bhoff = ((size_t)(b * NHEAD + h)) * S_LEN * HD_DIM;

    bf16x8 qf[4];
    {
        const size_t qrow = bhoff + (size_t)(q0 + wave * 16 + m16) * HD_DIM;
        #pragma unroll
        for (int kc = 0; kc < 4; kc++)
            qf[kc] = *(const bf16x8*)&Q[qrow + kc * 32 + quad * 8];
    }

    f32x4 o[8];
    #pragma unroll
    for (int i = 0; i < 8; i++) o[i] = (f32x4){0.f, 0.f, 0.f, 0.f};
    f32x4 m_i = {-1e30f, -1e30f, -1e30f, -1e30f};
    f32x4 l_i = {0.f, 0.f, 0.f, 0.f};

    const int row_g0 = q0 + wave * 16 + quad * 4;
    const float scale = 0.08838834764831843f;
    const int nt = (q0 >> 6) + 2;        // kv tiles to cover rows q0..q0+127

    const int krow = t >> 4, kd0 = (t & 15) << 3;  // K: rows krow, krow+32
    const int dg = t & 15, kvp = t >> 4;           // V: rows kvp*2, kvp*2+1
    const int vbase = (kvp & 3) << 1;

    uint4 kreg[2], vreg[2];
    kreg[0] = *(const uint4*)&K[bhoff + (size_t)(krow) * HD_DIM + kd0];
    kreg[1] = *(const uint4*)&K[bhoff + (size_t)(krow + 32) * HD_DIM + kd0];
    vreg[0] = *(const uint4*)&V[bhoff + (size_t)(kvp * 2) * HD_DIM + dg * 8];
    vreg[1] = *(const uint4*)&V[bhoff + (size_t)(kvp * 2 + 1) * HD_DIM + dg * 8];

    for (int it = 0; it < nt; ++it) {
        const int kb = it << 6;
        __syncthreads();
        *(uint4*)&k_s[(krow) * 136 + kd0]      = kreg[0];
        *(uint4*)&k_s[(krow + 32) * 136 + kd0] = kreg[1];
        {
            const u16* v0 = (const u16*)&vreg[0];
            const u16* v1 = (const u16*)&vreg[1];
            #pragma unroll
            for (int j = 0; j < 8; j++) {
                const int d = dg * 8 + j;
                const u32 w = (u32)v0[j] | ((u32)v1[j] << 16);
                *(u32*)&v_s[vswz(d, kvp >> 2) + vbase] = w;
            }
        }
        __syncthreads();
        if (it + 1 < nt) {
            const int kb2 = kb + 64;
            kreg[0] = *(const uint4*)&K[bhoff + (size_t)(kb2 + krow) * HD_DIM + kd0];
            kreg[1] = *(const uint4*)&K[bhoff + (size_t)(kb2 + krow + 32) * HD_DIM + kd0];
            vreg[0] = *(const uint4*)&V[bhoff + (size_t)(kb2 + kvp * 2) * HD_DIM + dg * 8];
            vreg[1] = *(const uint4*)&V[bhoff + (size_t)(kb2 + kvp * 2 + 1) * HD_DIM + dg * 8];
        }

        f32x4 s[4];
        #pragma unroll
        for (int f = 0; f < 4; f++) s[f] = (f32x4){0.f, 0.f, 0.f, 0.f};
        __builtin_amdgcn_s_setprio(1);
        #pragma unroll
        for (int kc = 0; kc < 4; kc++) {
            #pragma unroll
            for (int f = 0; f < 4; f++) {
                const bf16x8 kf = *(bf16x8*)&k_s[(f * 16 + m16) * 136 + kc * 32 + quad * 8];
                s[f] = __builtin_amdgcn_mfma_f32_16x16x32_bf16(qf[kc], kf, s[f], 0, 0, 0);
            }
        }
        __builtin_amdgcn_s_setprio(0);

        f32x4 mx;
        if (kb + 63 > row_g0) {
            #pragma unroll
            for (int r = 0; r < 4; r++) {
                float m0 = -1e30f;
                #pragma unroll
                for (int f = 0; f < 4; f++) {
                    float a = s[f][r] * scale;
                    if (kb + f * 16 + m16 > row_g0 + r) a = -1e30f;
                    s[f][r] = a;
                    m0 = fmaxf(m0, a);
                }
                mx[r] = m0;
            }
        } else {
            #pragma unroll
            for (int r = 0; r < 4; r++) {
                float m0 = -1e30f;
                #pragma unroll
                for (int f = 0; f < 4; f++) {
                    const float a = s[f][r] * scale;
                    s[f][r] = a;
                    m0 = fmaxf(m0, a);
                }
                mx[r] = m0;
            }
        }
        #pragma unroll
        for (int d = 1; d <= 8; d <<= 1)
            #pragma unroll
            for (int r = 0; r < 4; r++) mx[r] = fmaxf(mx[r], __shfl_xor(mx[r], d));

        f32x4 alpha, rs;
        #pragma unroll
        for (int r = 0; r < 4; r++) {
            const float mn = fmaxf(m_i[r], mx[r]);
            alpha[r] = __expf(m_i[r] - mn);
            m_i[r] = mn;
            float acc = 0.f;
            #pragma unroll
            for (int f = 0; f < 4; f++) {
                s[f][r] = __expf(s[f][r] - mn);
                acc += s[f][r];
            }
            rs[r] = acc;
        }
        #pragma unroll
        for (int d = 1; d <= 8; d <<= 1)
            #pragma unroll
            for (int r = 0; r < 4; r++) rs[r] += __shfl_xor(rs[r], d);
        #pragma unroll
        for (int r = 0; r < 4; r++) l_i[r] = l_i[r] * alpha[r] + rs[r];

        #pragma unroll
        for (int f = 0; f < 4; f++)
            #pragma unroll
            for (int r = 0; r < 4; r++)
                p_s[(wave * 16 + quad * 4 + r) * 72 + f * 16 + m16] = f2bf(s[f][r]);

        #pragma unroll
        for (int n = 0; n < 8; n++) o[n] *= alpha;

        __builtin_amdgcn_s_setprio(1);
        #pragma unroll
        for (int kc = 0; kc < 2; kc++) {
            const bf16x8 pa = *(bf16x8*)&p_s[(wave * 16 + m16) * 72 + kc * 32 + quad * 8];
            #pragma unroll
            for (int n = 0; n < 8; n++) {
                const int d = n * 16 + m16;
                const bf16x8 vb = *(bf16x8*)&v_s[vswz(d, kc * 4 + quad)];
                o[n] = __builtin_amdgcn_mfma_f32_16x16x32_bf16(pa, vb, o[n], 0, 0, 0);
            }
        }
        __builtin_amdgcn_s_setprio(0);
    }

    f32x4 inv;
    #pragma unroll
    for (int r = 0; r < 4; r++) inv[r] = 1.f / l_i[r];
    #pragma unroll
    for (int n = 0; n < 8; n++)
        #pragma unroll
        for (int r = 0; r < 4; r++)
            Out[bhoff + (size_t)(row_g0 + r) * HD_DIM + n * 16 + m16] =
                f2bf(o[n][r] * inv[r]);
}

// ---------- launch ----------
extern "C" void kernel_launch(void* const* d_in, const int* in_sizes, int n_in,
                              void* d_out, int out_size, void* d_ws, size_t ws_size,
                              hipStream_t stream) {
    float* outf = (float*)d_out;

    bool order_ok = (n_in == 11);
    if (order_ok) {
        const int expect[11] = {8388608, 8388608, 8388608, 4194304, 2048,
                                4194304, 2048, 4194304, 2048, 4194304, 2048};
        for (int i = 0; i < 11; i++) order_ok = order_ok && (in_sizes[i] == expect[i]);
    }
    if (!order_ok) {
        fill_k<<<dim3((out_size + 255) / 256), dim3(256), 0, stream>>>(outf, 50.f, out_size);
        return;
    }
    if (ws_size < (size_t)BSD * sizeof(u16)) {
        fill_k<<<dim3((out_size + 255) / 256), dim3(256), 0, stream>>>(outf, 25.f, out_size);
        return;
    }

    const void* queries = d_in[0];
    const void* keys    = d_in[1];
    const void* values  = d_in[2];
    const void* Wq = d_in[3]; const void* bq = d_in[4];
    const void* Wk = d_in[5]; const void* bk = d_in[6];
    const void* Wv = d_in[7]; const void* bv = d_in[8];
    const void* Wo = d_in[9]; const void* bo = d_in[10];

    const dim3 tb(256);
    const dim3 gr(16384, 2);

    const size_t wslot = (size_t)D_DIM * D_DIM * 2;               // 8.39 MB
    const size_t need_full  = (size_t)BSD * 8 + 3 * wslot;        // 92.3 MB (ws >= this, R4)

    if (ws_size >= need_full) {
        // FULL PATH: all-bf16 fused QKV GEMM (dbuf) + balanced 8-wave flash.
        u16* Qb = (u16*)d_ws;
        u16* Kb = Qb + BSD;
        u16* Vb = Kb + BSD;
        u16* WT = Vb + BSD;
        u16* XV = WT + 3 * (size_t)D_DIM * D_DIM;
        u16* XQ = (u16*)d_out;
        u16* XK = XQ + BSD;

        const dim3 gc3(4096, 3);
        const dim3 gt3(32, 32, 3);
        const dim3 gt(32, 32);
        const dim3 gq(16, 32, 3);
        const dim3 gb(16, 32);
        const dim3 gf8(S_LEN / 128, NHEAD, 2);
        const dim3 tb8(512);

        conv3<<<gc3, tb, 0, stream>>>(queries, keys, values, XQ, XK, XV);
        transpose_all<<<gt3, tb, 0, stream>>>(Wq, Wk, Wv, WT);
        qkv_gemm_bf<<<gq, tb, 0, stream>>>(XQ, XK, XV, WT, bq, bk, bv, Qb, Kb, Vb);
        transpose_w<<<gt, tb, 0, stream>>>(Wo, WT);   // slot 0 dead after qkv
        rope_k<<<gr, tb, 0, stream>>>(Qb, Kb);
        flash_mfma8<<<gf8, tb8, 0, stream>>>(Qb, Kb, Vb, Qb);
        bt_gemm<1><<<gb, tb, 0, stream>>>(Qb, WT, bo, outf);   // over dead XQ/XK
        return;
    }

    u16* Qb = (u16*)d_ws;
    u16* Kb = (u16*)d_out;
    u16* Vb = Kb + BSD;
    const dim3 gf(S_LEN / 64, NHEAD, 2);

    const size_t need_r3 = (size_t)BSD * 2 + 3 * wslot;           // 41.9 MB
    const size_t need_r2 = (size_t)BSD * 2 + wslot;               // 25.2 MB

    if (ws_size >= need_r3) {
        u16* WT = Qb + BSD;
        const dim3 gt3(32, 32, 3);
        const dim3 gt(32, 32);
        const dim3 gq(16, 32, 3);
        const dim3 gb(16, 32);

        transpose_all<<<gt3, tb, 0, stream>>>(Wq, Wk, Wv, WT);
        qkv_gemm<<<gq, tb, 0, stream>>>(queries, keys, values, WT,
                                        bq, bk, bv, Qb, Kb, Vb);
        transpose_w<<<gt, tb, 0, stream>>>(Wo, WT);
        rope_k<<<gr, tb, 0, stream>>>(Qb, Kb);
        flash_mfma<<<gf, tb, 0, stream>>>(Qb, Kb, Vb, Qb);
        bt_gemm<1><<<gb, tb, 0, stream>>>(Qb, WT, bo, outf);
    } else if (ws_size >= need_r2) {
        u16* WT = Qb + BSD;
        u16* XQ = Kb;
        u16* XK = Vb;
        const dim3 gt(32, 32);
        const dim3 gb(16, 32);
        const dim3 gc(4096);

        conv_bf16<<<gc, tb, 0, stream>>>(queries, XQ);
        conv_bf16<<<gc, tb, 0, stream>>>(keys, XK);

        transpose_w<<<gt, tb, 0, stream>>>(Wq, WT);
        bt_gemm<2><<<gb, tb, 0, stream>>>(XQ, WT, bq, Qb);
        transpose_w<<<gt, tb, 0, stream>>>(Wk, WT);
        bt_gemm<2><<<gb, tb, 0, stream>>>(XK, WT, bk, Kb);
        transpose_w<<<gt, tb, 0, stream>>>(Wv, WT);
        bt_gemm<0><<<gb, tb, 0, stream>>>(values, WT, bv, Vb);

        rope_k<<<gr, tb, 0, stream>>>(Qb, Kb);
        flash_mfma<<<gf, tb, 0, stream>>>(Qb, Kb, Vb, Qb);

        transpose_w<<<gt, tb, 0, stream>>>(Qb, WT);
        bt_gemm<1><<<gb, tb, 0, stream>>>(Qb, WT, bo, outf);
    } else {
        const dim3 gg(32, 64);
        gemm_qkv<<<gg, tb, 0, stream>>>(queries, Wq, bq, Qb);
        gemm_qkv<<<gg, tb, 0, stream>>>(keys,    Wk, bk, Kb);
        gemm_qkv<<<gg, tb, 0, stream>>>(values,  Wv, bv, Vb);
        rope_k<<<gr, tb, 0, stream>>>(Qb, Kb);
        flash_mfma<<<gf, tb, 0, stream>>>(Qb, Kb, Vb, Qb);
        gemm_o<<<gg, tb, 0, stream>>>(Qb, Wo, bo, outf);
    }
}